// Round 1
// baseline (2629.803 us; speedup 1.0000x reference)
//
#include <hip/hip_runtime.h>
#include <hip/hip_bf16.h>

// Problem constants (fixed by setup_inputs)
#define B_ 8
#define N_ 4096
#define E_ 2048
#define D_ 256
#define INF_SUB (-9.0e15f)

// ---------------- reductions ----------------
__device__ __forceinline__ float waveReduceSum(float v) {
#pragma unroll
    for (int o = 32; o > 0; o >>= 1) v += __shfl_xor(v, o, 64);
    return v;
}
__device__ __forceinline__ float waveReduceMax(float v) {
#pragma unroll
    for (int o = 32; o > 0; o >>= 1) v = fmaxf(v, __shfl_xor(v, o, 64));
    return v;
}

// ---------------- LayerNorm over D=256, one block per (b,e) row -------------
__global__ __launch_bounds__(256) void ln_kernel(const float* __restrict__ x,
                                                 const float* __restrict__ gamma,
                                                 const float* __restrict__ beta,
                                                 float* __restrict__ y) {
    __shared__ float red[8];
    const int row = blockIdx.x;
    const int t = threadIdx.x;
    const int lane = t & 63, wid = t >> 6;
    const float v = x[row * D_ + t];
    float s = waveReduceSum(v);
    if (lane == 0) red[wid] = s;
    __syncthreads();
    const float mu = (red[0] + red[1] + red[2] + red[3]) * (1.0f / D_);
    const float d = v - mu;
    float s2 = waveReduceSum(d * d);
    if (lane == 0) red[4 + wid] = s2;
    __syncthreads();
    const float var = (red[4] + red[5] + red[6] + red[7]) * (1.0f / D_);
    y[row * D_ + t] = gamma[t] * d * rsqrtf(var + 1e-5f) + beta[t];
}

// ---------------- masked softmax over n (4096), in-place on bf16 row --------
// row = b*E_+e ; sp layout [B,E,N] bf16 ; ht layout [B,E,N] int32 (same index)
__global__ __launch_bounds__(256) void masked_softmax_kernel(
        __hip_bfloat16* __restrict__ sp, const int* __restrict__ ht) {
    __shared__ float red[8];
    const int row = blockIdx.x;
    __hip_bfloat16* srow = sp + (size_t)row * N_;
    const int* hrow = ht + (size_t)row * N_;
    const int t = threadIdx.x;
    const int lane = t & 63, wid = t >> 6;

    float sv[16];
    float lmax = -3.0e38f;
#pragma unroll
    for (int i = 0; i < 16; ++i) {
        const int idx = t + i * 256;
        const float s = (hrow[idx] > 0) ? __bfloat162float(srow[idx]) : INF_SUB;
        sv[i] = s;
        lmax = fmaxf(lmax, s);
    }
    lmax = waveReduceMax(lmax);
    if (lane == 0) red[wid] = lmax;
    __syncthreads();
    const float m = fmaxf(fmaxf(red[0], red[1]), fmaxf(red[2], red[3]));
    float lsum = 0.f;
#pragma unroll
    for (int i = 0; i < 16; ++i) {
        sv[i] = __expf(sv[i] - m);  // masked: exp(-9e15 - m) -> 0 ; fully-masked row -> exp(0)=1
        lsum += sv[i];
    }
    lsum = waveReduceSum(lsum);
    if (lane == 0) red[4 + wid] = lsum;
    __syncthreads();
    const float inv = 1.0f / (red[4] + red[5] + red[6] + red[7]);
#pragma unroll
    for (int i = 0; i < 16; ++i)
        srow[t + i * 256] = __float2bfloat16(sv[i] * inv);
}

// ---------------- GEMM tiling common: 64x64 tile, BK=16, 4x4 micro ----------
#define BM 64
#define BN 64
#define BK 16
#define LDT 68  // padded LDS row stride (float4-aligned, <=2-way bank conflicts)

// C[M,Nc] = A[M,K] @ B[K,Nc]   (fp32 all; used for node_k and edge_k)
__global__ __launch_bounds__(256) void gemm_nn_f32(const float* __restrict__ A,
                                                   const float* __restrict__ Bm,
                                                   float* __restrict__ C,
                                                   int M, int Nc, int K) {
    __shared__ float As[BK][LDT];
    __shared__ float Bs[BK][LDT];
    const int tid = threadIdx.x;
    const int tx = tid & 15, ty = tid >> 4;
    const int row0 = blockIdx.y * BM, col0 = blockIdx.x * BN;
    const int ak = tid & 15, am0 = tid >> 4;   // A loader: k fast
    const int bn = tid & 63, bk0 = tid >> 6;   // B loader: n fast
    float acc[4][4] = {};
    for (int kt = 0; kt < K; kt += BK) {
#pragma unroll
        for (int p = 0; p < 4; ++p)
            As[ak][am0 + p * 16] = A[(row0 + am0 + p * 16) * K + kt + ak];
#pragma unroll
        for (int p = 0; p < 4; ++p)
            Bs[bk0 + p * 4][bn] = Bm[(kt + bk0 + p * 4) * Nc + col0 + bn];
        __syncthreads();
#pragma unroll
        for (int k = 0; k < BK; ++k) {
            const float4 a4 = *reinterpret_cast<const float4*>(&As[k][ty << 2]);
            const float4 b4 = *reinterpret_cast<const float4*>(&Bs[k][tx << 2]);
            const float a[4] = {a4.x, a4.y, a4.z, a4.w};
            const float b[4] = {b4.x, b4.y, b4.z, b4.w};
#pragma unroll
            for (int i = 0; i < 4; ++i)
#pragma unroll
                for (int j = 0; j < 4; ++j) acc[i][j] += a[i] * b[j];
        }
        __syncthreads();
    }
#pragma unroll
    for (int i = 0; i < 4; ++i) {
        float4 o = make_float4(acc[i][0], acc[i][1], acc[i][2], acc[i][3]);
        *reinterpret_cast<float4*>(&C[(row0 + ty * 4 + i) * Nc + col0 + tx * 4]) = o;
    }
}

// S[b][e,n] = alpha * Q[b][e,:] . Kn[b][n,:]   (NT, fp32 in, bf16 out)
// grid: (N_/64, E_/64, B_)
__global__ __launch_bounds__(256) void gemm_nt_scores(const float* __restrict__ Qb,
                                                      const float* __restrict__ Kb,
                                                      __hip_bfloat16* __restrict__ Sb,
                                                      float alpha) {
    const int b = blockIdx.z;
    const float* Q = Qb + (size_t)b * E_ * D_;
    const float* Kn = Kb + (size_t)b * N_ * D_;
    __hip_bfloat16* S = Sb + (size_t)b * E_ * N_;
    __shared__ float As[BK][LDT];
    __shared__ float Bs[BK][LDT];
    const int tid = threadIdx.x;
    const int tx = tid & 15, ty = tid >> 4;
    const int row0 = blockIdx.y * BM, col0 = blockIdx.x * BN;
    const int lk = tid & 15, lm0 = tid >> 4;  // both operands: k fast
    float acc[4][4] = {};
    for (int kt = 0; kt < D_; kt += BK) {
#pragma unroll
        for (int p = 0; p < 4; ++p)
            As[lk][lm0 + p * 16] = Q[(row0 + lm0 + p * 16) * D_ + kt + lk];
#pragma unroll
        for (int p = 0; p < 4; ++p)
            Bs[lk][lm0 + p * 16] = Kn[(col0 + lm0 + p * 16) * D_ + kt + lk];
        __syncthreads();
#pragma unroll
        for (int k = 0; k < BK; ++k) {
            const float4 a4 = *reinterpret_cast<const float4*>(&As[k][ty << 2]);
            const float4 b4 = *reinterpret_cast<const float4*>(&Bs[k][tx << 2]);
            const float a[4] = {a4.x, a4.y, a4.z, a4.w};
            const float b[4] = {b4.x, b4.y, b4.z, b4.w};
#pragma unroll
            for (int i = 0; i < 4; ++i)
#pragma unroll
                for (int j = 0; j < 4; ++j) acc[i][j] += a[i] * b[j];
        }
        __syncthreads();
    }
#pragma unroll
    for (int i = 0; i < 4; ++i)
#pragma unroll
        for (int j = 0; j < 4; ++j)
            S[(row0 + ty * 4 + i) * N_ + col0 + tx * 4 + j] =
                __float2bfloat16(acc[i][j] * alpha);
}

// edge_h[b][e,d] = sum_n P[b][e,n] * hidden[b][n,d] + eln[b][e,d]
// grid: (D_/64, E_/64, B_)   A bf16 [E,N], B fp32 [N,D]
__global__ __launch_bounds__(256) void gemm_pv(const __hip_bfloat16* __restrict__ Pb,
                                               const float* __restrict__ Hb,
                                               const float* __restrict__ addb,
                                               float* __restrict__ Cb) {
    const int b = blockIdx.z;
    const __hip_bfloat16* P = Pb + (size_t)b * E_ * N_;
    const float* H = Hb + (size_t)b * N_ * D_;
    const float* add = addb + (size_t)b * E_ * D_;
    float* C = Cb + (size_t)b * E_ * D_;
    __shared__ float As[BK][LDT];
    __shared__ float Bs[BK][LDT];
    const int tid = threadIdx.x;
    const int tx = tid & 15, ty = tid >> 4;
    const int row0 = blockIdx.y * BM, col0 = blockIdx.x * BN;
    const int ak = tid & 15, am0 = tid >> 4;
    const int bn = tid & 63, bk0 = tid >> 6;
    float acc[4][4] = {};
    for (int kt = 0; kt < N_; kt += BK) {
#pragma unroll
        for (int p = 0; p < 4; ++p)
            As[ak][am0 + p * 16] =
                __bfloat162float(P[(row0 + am0 + p * 16) * N_ + kt + ak]);
#pragma unroll
        for (int p = 0; p < 4; ++p)
            Bs[bk0 + p * 4][bn] = H[(kt + bk0 + p * 4) * D_ + col0 + bn];
        __syncthreads();
#pragma unroll
        for (int k = 0; k < BK; ++k) {
            const float4 a4 = *reinterpret_cast<const float4*>(&As[k][ty << 2]);
            const float4 b4 = *reinterpret_cast<const float4*>(&Bs[k][tx << 2]);
            const float a[4] = {a4.x, a4.y, a4.z, a4.w};
            const float b[4] = {b4.x, b4.y, b4.z, b4.w};
#pragma unroll
            for (int i = 0; i < 4; ++i)
#pragma unroll
                for (int j = 0; j < 4; ++j) acc[i][j] += a[i] * b[j];
        }
        __syncthreads();
    }
#pragma unroll
    for (int i = 0; i < 4; ++i) {
        const int r = row0 + ty * 4 + i;
        const int c = col0 + tx * 4;
        const float4 ad = *reinterpret_cast<const float4*>(&add[r * D_ + c]);
        float4 o = make_float4(acc[i][0] + ad.x, acc[i][1] + ad.y,
                               acc[i][2] + ad.z, acc[i][3] + ad.w);
        *reinterpret_cast<float4*>(&C[r * D_ + c]) = o;
    }
}

// out[b][n,d] = sum_e P2[b][e,n] * edge_h[b][e,d]   (TN: A accessed transposed)
// grid: (D_/64, N_/64, B_)
__global__ __launch_bounds__(256) void gemm_tn(const __hip_bfloat16* __restrict__ Pb,
                                               const float* __restrict__ EHb,
                                               float* __restrict__ Ob) {
    const int b = blockIdx.z;
    const __hip_bfloat16* P = Pb + (size_t)b * E_ * N_;
    const float* EH = EHb + (size_t)b * E_ * D_;
    float* O = Ob + (size_t)b * N_ * D_;
    __shared__ float As[BK][LDT];
    __shared__ float Bs[BK][LDT];
    const int tid = threadIdx.x;
    const int tx = tid & 15, ty = tid >> 4;
    const int row0 = blockIdx.y * BM, col0 = blockIdx.x * BN;
    const int am = tid & 63, ak0 = tid >> 6;  // A: m fast (A[k,m])
    const int bn = tid & 63, bk0 = tid >> 6;
    float acc[4][4] = {};
    for (int kt = 0; kt < E_; kt += BK) {
#pragma unroll
        for (int p = 0; p < 4; ++p)
            As[ak0 + p * 4][am] =
                __bfloat162float(P[(kt + ak0 + p * 4) * N_ + row0 + am]);
#pragma unroll
        for (int p = 0; p < 4; ++p)
            Bs[bk0 + p * 4][bn] = EH[(kt + bk0 + p * 4) * D_ + col0 + bn];
        __syncthreads();
#pragma unroll
        for (int k = 0; k < BK; ++k) {
            const float4 a4 = *reinterpret_cast<const float4*>(&As[k][ty << 2]);
            const float4 b4 = *reinterpret_cast<const float4*>(&Bs[k][tx << 2]);
            const float a[4] = {a4.x, a4.y, a4.z, a4.w};
            const float b[4] = {b4.x, b4.y, b4.z, b4.w};
#pragma unroll
            for (int i = 0; i < 4; ++i)
#pragma unroll
                for (int j = 0; j < 4; ++j) acc[i][j] += a[i] * b[j];
        }
        __syncthreads();
    }
#pragma unroll
    for (int i = 0; i < 4; ++i) {
        float4 o = make_float4(acc[i][0], acc[i][1], acc[i][2], acc[i][3]);
        *reinterpret_cast<float4*>(&O[(row0 + ty * 4 + i) * D_ + col0 + tx * 4]) = o;
    }
}

// ---------------------------------------------------------------------------
extern "C" void kernel_launch(void* const* d_in, const int* in_sizes, int n_in,
                              void* d_out, int out_size, void* d_ws, size_t ws_size,
                              hipStream_t stream) {
    const float* hidden = (const float*)d_in[0];    // [B,N,D]
    const int* ht = (const int*)d_in[1];            // [B,E,N]
    const float* edge_emb = (const float*)d_in[2];  // [B,E,D]
    const float* wnk = (const float*)d_in[3];       // [D,D]
    const float* wek = (const float*)d_in[4];       // [D,D]
    const float* gamma = (const float*)d_in[5];     // [D]
    const float* beta = (const float*)d_in[6];      // [D]
    float* out = (float*)d_out;                     // [B,N,D]

    // workspace carve (208 MB total)
    char* w = (char*)d_ws;
    __hip_bfloat16* SP = (__hip_bfloat16*)w;  w += (size_t)B_ * E_ * N_ * 2;  // 128MB, scores->probs in place
    float* node_k = (float*)w;                w += (size_t)B_ * N_ * D_ * 4;  // 32MB
    float* eln = (float*)w;                   w += (size_t)B_ * E_ * D_ * 4;  // 16MB
    float* edge_h = (float*)w;                w += (size_t)B_ * E_ * D_ * 4;  // 16MB
    float* edge_k = (float*)w;                w += (size_t)B_ * E_ * D_ * 4;  // 16MB
    (void)ws_size; (void)in_sizes; (void)n_in; (void)out_size;

    const float scale = 0.0625f;  // 1/sqrt(256)

    // 1. LayerNorm(edge_emb) -> eln
    ln_kernel<<<B_ * E_, 256, 0, stream>>>(edge_emb, gamma, beta, eln);
    // 2. node_k = hidden @ wnk   (all batches as one [B*N, D] GEMM)
    gemm_nn_f32<<<dim3(D_ / 64, (B_ * N_) / 64), 256, 0, stream>>>(
        hidden, wnk, node_k, B_ * N_, D_, D_);
    // 3. S1 = eln @ node_k^T * scale  -> SP (bf16)
    gemm_nt_scores<<<dim3(N_ / 64, E_ / 64, B_), 256, 0, stream>>>(
        eln, node_k, SP, scale);
    // 4. masked softmax over n, in place
    masked_softmax_kernel<<<B_ * E_, 256, 0, stream>>>(SP, ht);
    // 5. edge_h = P1 @ hidden + eln
    gemm_pv<<<dim3(D_ / 64, E_ / 64, B_), 256, 0, stream>>>(SP, hidden, eln, edge_h);
    // 6. edge_k = edge_h @ wek   ([B*E, D] GEMM)
    gemm_nn_f32<<<dim3(D_ / 64, (B_ * E_) / 64), 256, 0, stream>>>(
        edge_h, wek, edge_k, B_ * E_, D_, D_);
    // 7. S2 = edge_k @ node_k^T * scale -> SP (overwrite)
    gemm_nt_scores<<<dim3(N_ / 64, E_ / 64, B_), 256, 0, stream>>>(
        edge_k, node_k, SP, scale);
    // 8. masked softmax over n (axis=1 of [B,N,E] == n), in place
    masked_softmax_kernel<<<B_ * E_, 256, 0, stream>>>(SP, ht);
    // 9. out = P2^T @ edge_h
    gemm_tn<<<dim3(D_ / 64, N_ / 64, B_), 256, 0, stream>>>(SP, edge_h, out);
}

// Round 2
// 939.008 us; speedup vs baseline: 2.8006x; 2.8006x over previous
//
#include <hip/hip_runtime.h>
#include <hip/hip_bf16.h>
#include <stdint.h>

// R2: all big einsums -> bf16 MFMA (16x16x32), m97 structure:
//  128x128 block tile, 4 waves x (4x4) subtiles, BK=32, global_load_lds w=16,
//  k-chunk rotate swizzle (p = (kg + (row>>1)) & 3) for conflict-free ds_read_b128.
//  Mask packed to bits; softmax applies mask (no 268MB int32 re-read).

#define B_ 8
#define N_ 4096
#define E_ 2048
#define D_ 256
#define INF_SUB (-9.0e15f)

typedef short bf16x8 __attribute__((ext_vector_type(8)));
typedef float f32x4 __attribute__((ext_vector_type(4)));
typedef unsigned short us8 __attribute__((ext_vector_type(8)));

#define AS1 __attribute__((address_space(1)))
#define AS3 __attribute__((address_space(3)))

__device__ __forceinline__ unsigned short f2bf(float f) {
    union { float f; unsigned int u; } v; v.f = f;
    unsigned int r = v.u + 0x7fffu + ((v.u >> 16) & 1u);
    return (unsigned short)(r >> 16);
}
__device__ __forceinline__ float bf2f(unsigned short h) {
    union { unsigned int u; float f; } v; v.u = ((unsigned int)h) << 16;
    return v.f;
}
__device__ __forceinline__ float waveReduceSum(float v) {
#pragma unroll
    for (int o = 32; o > 0; o >>= 1) v += __shfl_xor(v, o, 64);
    return v;
}
__device__ __forceinline__ float waveReduceMax(float v) {
#pragma unroll
    for (int o = 32; o > 0; o >>= 1) v = fmaxf(v, __shfl_xor(v, o, 64));
    return v;
}

// ---------------- LayerNorm over D=256: writes f32 + bf16 -------------------
__global__ __launch_bounds__(256) void ln_kernel(const float* __restrict__ x,
                                                 const float* __restrict__ gamma,
                                                 const float* __restrict__ beta,
                                                 float* __restrict__ y,
                                                 unsigned short* __restrict__ yb) {
    __shared__ float red[8];
    const int row = blockIdx.x;
    const int t = threadIdx.x;
    const int lane = t & 63, wid = t >> 6;
    const float v = x[(size_t)row * D_ + t];
    float s = waveReduceSum(v);
    if (lane == 0) red[wid] = s;
    __syncthreads();
    const float mu = (red[0] + red[1] + red[2] + red[3]) * (1.0f / D_);
    const float d = v - mu;
    float s2 = waveReduceSum(d * d);
    if (lane == 0) red[4 + wid] = s2;
    __syncthreads();
    const float var = (red[4] + red[5] + red[6] + red[7]) * (1.0f / D_);
    const float o = gamma[t] * d * rsqrtf(var + 1e-5f) + beta[t];
    y[(size_t)row * D_ + t] = o;
    yb[(size_t)row * D_ + t] = f2bf(o);
}

// ---------------- pack ht -> bitmask (bit = col&31 of word col>>5) ----------
__global__ __launch_bounds__(256) void pack_mask(const int* __restrict__ ht,
                                                 uint32_t* __restrict__ bits) {
    const int row = blockIdx.x;
    const int t = threadIdx.x, wid = t >> 6, lane = t & 63;
    const int* hrow = ht + (size_t)row * N_;
    uint32_t* brow = bits + (size_t)row * (N_ / 32);
#pragma unroll
    for (int i = 0; i < 16; ++i) {
        const int c = wid * 16 + i;  // chunk of 64 cols
        const int v = hrow[c * 64 + lane];
        unsigned long long m = __ballot(v > 0);
        if (lane == 0) {
            brow[c * 2] = (uint32_t)m;
            brow[c * 2 + 1] = (uint32_t)(m >> 32);
        }
    }
}

// ---------------- masked softmax over n=4096, bf16 in/out, bit mask ---------
__global__ __launch_bounds__(256) void softmax_bits(unsigned short* __restrict__ sp,
                                                    const uint32_t* __restrict__ bits) {
    __shared__ float red[8];
    __shared__ uint32_t mw[128];
    const int row = blockIdx.x;
    unsigned short* srow = sp + (size_t)row * N_;
    const int t = threadIdx.x, lane = t & 63, wid = t >> 6;
    if (t < 128) mw[t] = bits[(size_t)row * 128 + t];
    __syncthreads();
    const uint32_t w32 = mw[t >> 1];
    const uint32_t mbits = (w32 >> ((t & 1) * 16)) & 0xffffu;
    us8 v[2];
    v[0] = *(const us8*)&srow[t * 16];
    v[1] = *(const us8*)&srow[t * 16 + 8];
    float sv[16];
    float lmax = -3.0e38f;
#pragma unroll
    for (int i = 0; i < 16; ++i) {
        const float s = ((mbits >> i) & 1u) ? bf2f(v[i >> 3][i & 7]) : INF_SUB;
        sv[i] = s;
        lmax = fmaxf(lmax, s);
    }
    lmax = waveReduceMax(lmax);
    if (lane == 0) red[wid] = lmax;
    __syncthreads();
    const float m = fmaxf(fmaxf(red[0], red[1]), fmaxf(red[2], red[3]));
    float lsum = 0.f;
#pragma unroll
    for (int i = 0; i < 16; ++i) {
        sv[i] = __expf(sv[i] - m);
        lsum += sv[i];
    }
    lsum = waveReduceSum(lsum);
    if (lane == 0) red[4 + wid] = lsum;
    __syncthreads();
    const float inv = 1.0f / (red[4] + red[5] + red[6] + red[7]);
    us8 o[2];
#pragma unroll
    for (int i = 0; i < 16; ++i) o[i >> 3][i & 7] = f2bf(sv[i] * inv);
    *(us8*)&srow[t * 16] = o[0];
    *(us8*)&srow[t * 16 + 8] = o[1];
}

// ---------------- fp32 [N,D] -> bf16 [N,D] + bf16 [D,N] (transpose) --------
__global__ __launch_bounds__(256) void prep_hidden(const float* __restrict__ in,
                                                   unsigned short* __restrict__ hb,
                                                   unsigned short* __restrict__ hT) {
    __shared__ unsigned short tile[64][65];
    const int b = blockIdx.z;
    in += (size_t)b * N_ * D_;
    hb += (size_t)b * N_ * D_;
    hT += (size_t)b * D_ * N_;
    const int n0 = blockIdx.y * 64, d0 = blockIdx.x * 64;
    const int t = threadIdx.x;
    const int tr = t >> 4, tc = (t & 15) * 4;
#pragma unroll
    for (int q = 0; q < 4; ++q) {
        const int rr = q * 16 + tr;
        const float4 f = *(const float4*)&in[(size_t)(n0 + rr) * D_ + d0 + tc];
        us8 dummy;  // (unused)
        unsigned short h0 = f2bf(f.x), h1 = f2bf(f.y), h2 = f2bf(f.z), h3 = f2bf(f.w);
        ushort4 hv = make_ushort4(h0, h1, h2, h3);
        *(ushort4*)&hb[(size_t)(n0 + rr) * D_ + d0 + tc] = hv;
        tile[rr][tc + 0] = h0; tile[rr][tc + 1] = h1;
        tile[rr][tc + 2] = h2; tile[rr][tc + 3] = h3;
        (void)dummy;
    }
    __syncthreads();
#pragma unroll
    for (int q = 0; q < 4; ++q) {
        const int cc = q * 16 + tr;  // original col -> out row
        ushort4 o = make_ushort4(tile[tc + 0][cc], tile[tc + 1][cc],
                                 tile[tc + 2][cc], tile[tc + 3][cc]);
        *(ushort4*)&hT[(size_t)(d0 + cc) * N_ + n0 + tc] = o;
    }
}

// ---------------- generic bf16 transpose: in[R,C] -> out[C,R], batched ------
__global__ __launch_bounds__(256) void transpose_bf(const unsigned short* __restrict__ in,
                                                    unsigned short* __restrict__ out,
                                                    int R, int C, size_t sIn, size_t sOut) {
    __shared__ unsigned short tile[64][65];
    const int b = blockIdx.z;
    in += (size_t)b * sIn;
    out += (size_t)b * sOut;
    const int r0 = blockIdx.y * 64, c0 = blockIdx.x * 64;
    const int t = threadIdx.x;
    const int tr = t >> 4, tc = (t & 15) * 4;
#pragma unroll
    for (int q = 0; q < 4; ++q) {
        const int rr = q * 16 + tr;
        const ushort4 v = *(const ushort4*)&in[(size_t)(r0 + rr) * C + c0 + tc];
        tile[rr][tc + 0] = v.x; tile[rr][tc + 1] = v.y;
        tile[rr][tc + 2] = v.z; tile[rr][tc + 3] = v.w;
    }
    __syncthreads();
#pragma unroll
    for (int q = 0; q < 4; ++q) {
        const int cc = q * 16 + tr;
        ushort4 o = make_ushort4(tile[tc + 0][cc], tile[tc + 1][cc],
                                 tile[tc + 2][cc], tile[tc + 3][cc]);
        *(ushort4*)&out[(size_t)(c0 + cc) * R + r0 + tc] = o;
    }
}

// ---------------- tiny: w[D,D] f32 -> wT[D,D] bf16 --------------------------
__global__ __launch_bounds__(256) void cast_wT(const float* __restrict__ w,
                                               unsigned short* __restrict__ wT) {
    const int gid = blockIdx.x * 256 + threadIdx.x;
    const int i = gid >> 8, j = gid & 255;
    wT[j * D_ + i] = f2bf(w[i * D_ + j]);
}

// ---------------- MFMA NT GEMM: C[m,n] = sum_k A[m,k]*Bt[n,k] ---------------
// A: bf16 [M,K] lda=K ; Bt: bf16 [Nc,K] ldb=K ; 128x128 tile, BK=32.
#define MODE_BF16 0
#define MODE_SCALE 1
#define MODE_ADD 2
#define MODE_F32 3

template <int MODE>
__global__ __launch_bounds__(256) void mfma_gemm_nt(
        const short* __restrict__ A, const short* __restrict__ Bm,
        void* __restrict__ Cv, const float* __restrict__ Add,
        int K, int ldc, size_t sA, size_t sB, size_t sC, float scale) {
    __shared__ __align__(16) short lsA[128 * 32];
    __shared__ __align__(16) short lsB[128 * 32];
    const int b = blockIdx.z;
    A += (size_t)b * sA;
    Bm += (size_t)b * sB;
    const int m0 = blockIdx.y * 128, n0 = blockIdx.x * 128;
    const int tid = threadIdx.x, wid = tid >> 6, lane = tid & 63;
    const int l15 = lane & 15, kg = lane >> 4;
    const int wr = wid >> 1, wc = wid & 1;

    // frag LDS element offsets (swizzle: chunk pos p = (kg + (row>>1)) & 3)
    int aoff[4], boff[4];
#pragma unroll
    for (int i = 0; i < 4; ++i) {
        const int ra = wr * 64 + i * 16 + l15;
        aoff[i] = ra * 32 + (((kg + (ra >> 1)) & 3) << 3);
        const int rb = wc * 64 + i * 16 + l15;
        boff[i] = rb * 32 + (((kg + (rb >> 1)) & 3) << 3);
    }
    const f32x4 zero = {0.f, 0.f, 0.f, 0.f};
    f32x4 acc[4][4];
#pragma unroll
    for (int i = 0; i < 4; ++i)
#pragma unroll
        for (int j = 0; j < 4; ++j) acc[i][j] = zero;

    for (int kt = 0; kt < K; kt += 32) {
        __syncthreads();  // all waves done reading previous tile
#pragma unroll
        for (int q = 0; q < 2; ++q) {
            const int c = q * 256 + tid;
            const int r = c >> 2;
            const int kc = ((c & 3) - (r >> 1)) & 3;  // global k-chunk this LDS slot holds
            const short* ga = A + (size_t)(m0 + r) * K + kt + kc * 8;
            __builtin_amdgcn_global_load_lds((const AS1 void*)ga,
                (AS3 void*)(lsA + (q * 256 + wid * 64) * 8), 16, 0, 0);
            const short* gb = Bm + (size_t)(n0 + r) * K + kt + kc * 8;
            __builtin_amdgcn_global_load_lds((const AS1 void*)gb,
                (AS3 void*)(lsB + (q * 256 + wid * 64) * 8), 16, 0, 0);
        }
        __syncthreads();  // loads landed
        bf16x8 fa[4], fb[4];
#pragma unroll
        for (int i = 0; i < 4; ++i) fa[i] = *(const bf16x8*)(lsA + aoff[i]);
#pragma unroll
        for (int j = 0; j < 4; ++j) fb[j] = *(const bf16x8*)(lsB + boff[j]);
#pragma unroll
        for (int i = 0; i < 4; ++i)
#pragma unroll
            for (int j = 0; j < 4; ++j)
                acc[i][j] = __builtin_amdgcn_mfma_f32_16x16x32_bf16(fa[i], fb[j], acc[i][j], 0, 0, 0);
    }

    // epilogue: C/D layout: col = lane&15, row = (lane>>4)*4 + reg  [m89/m91]
    if (MODE == MODE_F32) {
        float* C = (float*)Cv + (size_t)b * sC;
#pragma unroll
        for (int i = 0; i < 4; ++i)
#pragma unroll
            for (int j = 0; j < 4; ++j) {
                const int col = n0 + wc * 64 + j * 16 + l15;
#pragma unroll
                for (int r = 0; r < 4; ++r) {
                    const int row = m0 + wr * 64 + i * 16 + kg * 4 + r;
                    C[(size_t)row * ldc + col] = acc[i][j][r];
                }
            }
    } else {
        unsigned short* C = (unsigned short*)Cv + (size_t)b * sC;
        const float* Ab = (MODE == MODE_ADD) ? (Add + (size_t)b * sC) : nullptr;
#pragma unroll
        for (int i = 0; i < 4; ++i)
#pragma unroll
            for (int j = 0; j < 4; ++j) {
                const int col = n0 + wc * 64 + j * 16 + l15;
#pragma unroll
                for (int r = 0; r < 4; ++r) {
                    const int row = m0 + wr * 64 + i * 16 + kg * 4 + r;
                    float v = acc[i][j][r];
                    if (MODE == MODE_SCALE) v *= scale;
                    if (MODE == MODE_ADD) v += Ab[(size_t)row * ldc + col];
                    C[(size_t)row * ldc + col] = f2bf(v);
                }
            }
    }
}

// ---------------------------------------------------------------------------
extern "C" void kernel_launch(void* const* d_in, const int* in_sizes, int n_in,
                              void* d_out, int out_size, void* d_ws, size_t ws_size,
                              hipStream_t stream) {
    const float* hidden = (const float*)d_in[0];    // [B,N,D]
    const int* ht = (const int*)d_in[1];            // [B,E,N]
    const float* edge_emb = (const float*)d_in[2];  // [B,E,D]
    const float* wnk = (const float*)d_in[3];       // [D,D]
    const float* wek = (const float*)d_in[4];       // [D,D]
    const float* gamma = (const float*)d_in[5];     // [D]
    const float* beta = (const float*)d_in[6];      // [D]
    float* out = (float*)d_out;                     // [B,N,D]
    (void)in_sizes; (void)n_in; (void)out_size; (void)ws_size;

    // workspace carve (~378 MB)
    char* w = (char*)d_ws;
    unsigned short* SP = (unsigned short*)w;   w += (size_t)B_ * E_ * N_ * 2;   // 134 MB
    unsigned short* P2T = (unsigned short*)w;  w += (size_t)B_ * N_ * E_ * 2;   // 134 MB
    unsigned short* hidden_bf = (unsigned short*)w;  w += (size_t)B_ * N_ * D_ * 2;  // 16.8
    unsigned short* hiddenT_bf = (unsigned short*)w; w += (size_t)B_ * D_ * N_ * 2;  // 16.8
    unsigned short* node_k_bf = (unsigned short*)w;  w += (size_t)B_ * N_ * D_ * 2;  // 16.8
    float* eln_f = (float*)w;                  w += (size_t)B_ * E_ * D_ * 4;   // 16.8
    unsigned short* eln_bf = (unsigned short*)w;     w += (size_t)B_ * E_ * D_ * 2;  // 8.4
    unsigned short* edge_h_bf = (unsigned short*)w;  w += (size_t)B_ * E_ * D_ * 2;  // 8.4
    unsigned short* edge_hT_bf = (unsigned short*)w; w += (size_t)B_ * D_ * E_ * 2;  // 8.4
    unsigned short* edge_k_bf = (unsigned short*)w;  w += (size_t)B_ * E_ * D_ * 2;  // 8.4
    uint32_t* bits = (uint32_t*)w;             w += (size_t)B_ * E_ * (N_ / 32) * 4; // 8.4
    unsigned short* wnkT = (unsigned short*)w; w += (size_t)D_ * D_ * 2;
    unsigned short* wekT = (unsigned short*)w; w += (size_t)D_ * D_ * 2;

    const float scale = 0.0625f;  // 1/sqrt(256)

    // prep
    prep_hidden<<<dim3(D_ / 64, N_ / 64, B_), 256, 0, stream>>>(hidden, hidden_bf, hiddenT_bf);
    cast_wT<<<D_ * D_ / 256, 256, 0, stream>>>(wnk, wnkT);
    cast_wT<<<D_ * D_ / 256, 256, 0, stream>>>(wek, wekT);
    ln_kernel<<<B_ * E_, 256, 0, stream>>>(edge_emb, gamma, beta, eln_f, eln_bf);
    pack_mask<<<B_ * E_, 256, 0, stream>>>(ht, bits);

    // node_k = hidden @ wnk  (flattened [B*N, D] x [D, D]^T-laid-out)
    mfma_gemm_nt<MODE_BF16><<<dim3(D_ / 128, (B_ * N_) / 128, 1), 256, 0, stream>>>(
        (const short*)hidden_bf, (const short*)wnkT, node_k_bf, nullptr,
        D_, D_, 0, 0, 0, 1.f);
    // S1 = eln @ node_k^T * scale
    mfma_gemm_nt<MODE_SCALE><<<dim3(N_ / 128, E_ / 128, B_), 256, 0, stream>>>(
        (const short*)eln_bf, (const short*)node_k_bf, SP, nullptr,
        D_, N_, (size_t)E_ * D_, (size_t)N_ * D_, (size_t)E_ * N_, scale);
    softmax_bits<<<B_ * E_, 256, 0, stream>>>(SP, bits);
    // edge_h = P1 @ hidden + eln   (B-operand = hidden^T [D,N])
    mfma_gemm_nt<MODE_ADD><<<dim3(D_ / 128, E_ / 128, B_), 256, 0, stream>>>(
        (const short*)SP, (const short*)hiddenT_bf, edge_h_bf, eln_f,
        N_, D_, (size_t)E_ * N_, (size_t)D_ * N_, (size_t)E_ * D_, 1.f);
    transpose_bf<<<dim3(D_ / 64, E_ / 64, B_), 256, 0, stream>>>(
        edge_h_bf, edge_hT_bf, E_, D_, (size_t)E_ * D_, (size_t)D_ * E_);
    // edge_k = edge_h @ wek
    mfma_gemm_nt<MODE_BF16><<<dim3(D_ / 128, (B_ * E_) / 128, 1), 256, 0, stream>>>(
        (const short*)edge_h_bf, (const short*)wekT, edge_k_bf, nullptr,
        D_, D_, 0, 0, 0, 1.f);
    // S2 = edge_k @ node_k^T * scale
    mfma_gemm_nt<MODE_SCALE><<<dim3(N_ / 128, E_ / 128, B_), 256, 0, stream>>>(
        (const short*)edge_k_bf, (const short*)node_k_bf, SP, nullptr,
        D_, N_, (size_t)E_ * D_, (size_t)N_ * D_, (size_t)E_ * N_, scale);
    softmax_bits<<<B_ * E_, 256, 0, stream>>>(SP, bits);
    // P2T [N,E] for the TN contraction
    transpose_bf<<<dim3(N_ / 64, E_ / 64, B_), 256, 0, stream>>>(
        SP, P2T, E_, N_, (size_t)E_ * N_, (size_t)N_ * E_);
    // out = P2^T @ edge_h  (A = P2T [N,E], B = edge_h^T [D,E])
    mfma_gemm_nt<MODE_F32><<<dim3(D_ / 128, N_ / 128, B_), 256, 0, stream>>>(
        (const short*)P2T, (const short*)edge_hT_bf, out, nullptr,
        E_, D_, (size_t)N_ * E_, (size_t)D_ * E_, (size_t)N_ * D_, 1.f);
}

// Round 3
// 925.556 us; speedup vs baseline: 2.8413x; 1.0145x over previous
//
#include <hip/hip_runtime.h>
#include <hip/hip_bf16.h>
#include <stdint.h>

// R3: coalesced LDS-repack epilogues on all MFMA GEMMs; stage-2 computed as
// S2T [N,E] with mask + column exp-sum (softmax denominator) fused into the
// GEMM epilogue (atomicAdd per column); P2T transpose and softmax2 kernels
// replaced by one light exp-apply kernel. Stage-1 path unchanged (proven).

#define B_ 8
#define N_ 4096
#define E_ 2048
#define D_ 256
#define INF_SUB (-9.0e15f)

typedef short bf16x8 __attribute__((ext_vector_type(8)));
typedef float f32x4 __attribute__((ext_vector_type(4)));
typedef unsigned short us8 __attribute__((ext_vector_type(8)));

#define AS1 __attribute__((address_space(1)))
#define AS3 __attribute__((address_space(3)))

__device__ __forceinline__ unsigned short f2bf(float f) {
    union { float f; unsigned int u; } v; v.f = f;
    unsigned int r = v.u + 0x7fffu + ((v.u >> 16) & 1u);
    return (unsigned short)(r >> 16);
}
__device__ __forceinline__ float bf2f(unsigned short h) {
    union { unsigned int u; float f; } v; v.u = ((unsigned int)h) << 16;
    return v.f;
}
__device__ __forceinline__ float waveReduceSum(float v) {
#pragma unroll
    for (int o = 32; o > 0; o >>= 1) v += __shfl_xor(v, o, 64);
    return v;
}
__device__ __forceinline__ float waveReduceMax(float v) {
#pragma unroll
    for (int o = 32; o > 0; o >>= 1) v = fmaxf(v, __shfl_xor(v, o, 64));
    return v;
}

// ---------------- LayerNorm over D=256 -> bf16 ------------------------------
__global__ __launch_bounds__(256) void ln_kernel(const float* __restrict__ x,
                                                 const float* __restrict__ gamma,
                                                 const float* __restrict__ beta,
                                                 unsigned short* __restrict__ yb) {
    __shared__ float red[8];
    const int row = blockIdx.x;
    const int t = threadIdx.x;
    const int lane = t & 63, wid = t >> 6;
    const float v = x[(size_t)row * D_ + t];
    float s = waveReduceSum(v);
    if (lane == 0) red[wid] = s;
    __syncthreads();
    const float mu = (red[0] + red[1] + red[2] + red[3]) * (1.0f / D_);
    const float d = v - mu;
    float s2 = waveReduceSum(d * d);
    if (lane == 0) red[4 + wid] = s2;
    __syncthreads();
    const float var = (red[4] + red[5] + red[6] + red[7]) * (1.0f / D_);
    yb[(size_t)row * D_ + t] = f2bf(gamma[t] * d * rsqrtf(var + 1e-5f) + beta[t]);
}

// ---------------- pack ht -> bitmask: bits[b][e][n>>5] bit (n&31) -----------
__global__ __launch_bounds__(256) void pack_mask(const int* __restrict__ ht,
                                                 uint32_t* __restrict__ bits) {
    const int row = blockIdx.x;
    const int t = threadIdx.x, wid = t >> 6, lane = t & 63;
    const int* hrow = ht + (size_t)row * N_;
    uint32_t* brow = bits + (size_t)row * (N_ / 32);
#pragma unroll
    for (int i = 0; i < 16; ++i) {
        const int c = wid * 16 + i;
        const int v = hrow[c * 64 + lane];
        unsigned long long m = __ballot(v > 0);
        if (lane == 0) {
            brow[c * 2] = (uint32_t)m;
            brow[c * 2 + 1] = (uint32_t)(m >> 32);
        }
    }
}

// ---------------- stage-1 masked softmax over n=4096 (row layout [E,N]) -----
__global__ __launch_bounds__(256) void softmax_bits(unsigned short* __restrict__ sp,
                                                    const uint32_t* __restrict__ bits) {
    __shared__ float red[8];
    __shared__ uint32_t mw[128];
    const int row = blockIdx.x;
    unsigned short* srow = sp + (size_t)row * N_;
    const int t = threadIdx.x, lane = t & 63, wid = t >> 6;
    if (t < 128) mw[t] = bits[(size_t)row * 128 + t];
    __syncthreads();
    const uint32_t w32 = mw[t >> 1];
    const uint32_t mbits = (w32 >> ((t & 1) * 16)) & 0xffffu;
    us8 v[2];
    v[0] = *(const us8*)&srow[t * 16];
    v[1] = *(const us8*)&srow[t * 16 + 8];
    float sv[16];
    float lmax = -3.0e38f;
#pragma unroll
    for (int i = 0; i < 16; ++i) {
        const float s = ((mbits >> i) & 1u) ? bf2f(v[i >> 3][i & 7]) : INF_SUB;
        sv[i] = s;
        lmax = fmaxf(lmax, s);
    }
    lmax = waveReduceMax(lmax);
    if (lane == 0) red[wid] = lmax;
    __syncthreads();
    const float m = fmaxf(fmaxf(red[0], red[1]), fmaxf(red[2], red[3]));
    float lsum = 0.f;
#pragma unroll
    for (int i = 0; i < 16; ++i) {
        sv[i] = __expf(sv[i] - m);
        lsum += sv[i];
    }
    lsum = waveReduceSum(lsum);
    if (lane == 0) red[4 + wid] = lsum;
    __syncthreads();
    const float inv = 1.0f / (red[4] + red[5] + red[6] + red[7]);
    us8 o[2];
#pragma unroll
    for (int i = 0; i < 16; ++i) o[i >> 3][i & 7] = f2bf(sv[i] * inv);
    *(us8*)&srow[t * 16] = o[0];
    *(us8*)&srow[t * 16 + 8] = o[1];
}

// ---------------- stage-2 apply: p = exp(s) / lsum[e], in place [N,E] -------
__global__ __launch_bounds__(256) void apply_colsoftmax(unsigned short* __restrict__ S,
                                                        const float* __restrict__ lsum) {
    const int b = blockIdx.z;
    const int t = threadIdx.x;
    const int n0 = blockIdx.y * 32;
    unsigned short* p = S + (size_t)b * N_ * E_ + (size_t)n0 * E_ + t * 8;
    const float* lp = lsum + (size_t)b * E_ + t * 8;
    float invl[8];
#pragma unroll
    for (int j = 0; j < 8; ++j) invl[j] = 1.0f / lp[j];
    for (int i = 0; i < 32; ++i) {
        us8 v = *(us8*)&p[(size_t)i * E_];
        us8 o;
#pragma unroll
        for (int j = 0; j < 8; ++j) o[j] = f2bf(__expf(bf2f(v[j])) * invl[j]);
        *(us8*)&p[(size_t)i * E_] = o;
    }
}

// ---------------- fp32 [N,D] -> bf16 [N,D] + bf16 [D,N] ---------------------
__global__ __launch_bounds__(256) void prep_hidden(const float* __restrict__ in,
                                                   unsigned short* __restrict__ hb,
                                                   unsigned short* __restrict__ hT) {
    __shared__ unsigned short tile[64][65];
    const int b = blockIdx.z;
    in += (size_t)b * N_ * D_;
    hb += (size_t)b * N_ * D_;
    hT += (size_t)b * D_ * N_;
    const int n0 = blockIdx.y * 64, d0 = blockIdx.x * 64;
    const int t = threadIdx.x;
    const int tr = t >> 4, tc = (t & 15) * 4;
#pragma unroll
    for (int q = 0; q < 4; ++q) {
        const int rr = q * 16 + tr;
        const float4 f = *(const float4*)&in[(size_t)(n0 + rr) * D_ + d0 + tc];
        unsigned short h0 = f2bf(f.x), h1 = f2bf(f.y), h2 = f2bf(f.z), h3 = f2bf(f.w);
        *(ushort4*)&hb[(size_t)(n0 + rr) * D_ + d0 + tc] = make_ushort4(h0, h1, h2, h3);
        tile[rr][tc + 0] = h0; tile[rr][tc + 1] = h1;
        tile[rr][tc + 2] = h2; tile[rr][tc + 3] = h3;
    }
    __syncthreads();
#pragma unroll
    for (int q = 0; q < 4; ++q) {
        const int cc = q * 16 + tr;
        ushort4 o = make_ushort4(tile[tc + 0][cc], tile[tc + 1][cc],
                                 tile[tc + 2][cc], tile[tc + 3][cc]);
        *(ushort4*)&hT[(size_t)(d0 + cc) * N_ + n0 + tc] = o;
    }
}

// ---------------- generic bf16 transpose (edge_h -> edge_hT) ----------------
__global__ __launch_bounds__(256) void transpose_bf(const unsigned short* __restrict__ in,
                                                    unsigned short* __restrict__ out,
                                                    int R, int C, size_t sIn, size_t sOut) {
    __shared__ unsigned short tile[64][65];
    const int b = blockIdx.z;
    in += (size_t)b * sIn;
    out += (size_t)b * sOut;
    const int r0 = blockIdx.y * 64, c0 = blockIdx.x * 64;
    const int t = threadIdx.x;
    const int tr = t >> 4, tc = (t & 15) * 4;
#pragma unroll
    for (int q = 0; q < 4; ++q) {
        const int rr = q * 16 + tr;
        const ushort4 v = *(const ushort4*)&in[(size_t)(r0 + rr) * C + c0 + tc];
        tile[rr][tc + 0] = v.x; tile[rr][tc + 1] = v.y;
        tile[rr][tc + 2] = v.z; tile[rr][tc + 3] = v.w;
    }
    __syncthreads();
#pragma unroll
    for (int q = 0; q < 4; ++q) {
        const int cc = q * 16 + tr;
        ushort4 o = make_ushort4(tile[tc + 0][cc], tile[tc + 1][cc],
                                 tile[tc + 2][cc], tile[tc + 3][cc]);
        *(ushort4*)&out[(size_t)(c0 + cc) * R + r0 + tc] = o;
    }
}

// ---------------- tiny: w[D,D] f32 -> wT[D,D] bf16 --------------------------
__global__ __launch_bounds__(256) void cast_wT(const float* __restrict__ w,
                                               unsigned short* __restrict__ wT) {
    const int gid = blockIdx.x * 256 + threadIdx.x;
    const int i = gid >> 8, j = gid & 255;
    wT[j * D_ + i] = f2bf(w[i * D_ + j]);
}

// ---------------- MFMA NT GEMM: C[m,n] = sum_k A[m,k]*Bt[n,k] ---------------
// 128x128 tile, BK=32, global_load_lds w=16, swizzled LDS, LDS-repack epilogue.
#define M_BF16 0   // bf16 out
#define M_SCALE 1  // bf16 out, *scale (optionally +mask+colsum via MASKSUM)
#define M_ADD 2    // bf16 out, + bf16 addend
#define M_F32 3    // f32 out

template <int MODE, int MASKSUM>
__global__ __launch_bounds__(256) void mfma_gemm_nt(
        const short* __restrict__ A, const short* __restrict__ Bm,
        void* __restrict__ Cv, const unsigned short* __restrict__ Add,
        const uint32_t* __restrict__ bits, float* __restrict__ lsum,
        int K, int ldc, size_t sA, size_t sB, size_t sC, float scale) {
    __shared__ __align__(16) short ls[8192];       // 16 KB: lsA | lsB, reused by repack
    __shared__ uint32_t mwords[512];               // mask words (MASKSUM only)
    short* lsA = ls;
    short* lsB = ls + 4096;
    const int b = blockIdx.z;
    A += (size_t)b * sA;
    Bm += (size_t)b * sB;
    const int m0 = blockIdx.y * 128, n0 = blockIdx.x * 128;
    const int tid = threadIdx.x, wid = tid >> 6, lane = tid & 63;
    const int l15 = lane & 15, kg = lane >> 4;
    const int wr = wid >> 1, wc = wid & 1;

    if (MASKSUM) {
        const uint32_t* bb = bits + (size_t)b * E_ * (N_ / 32);
#pragma unroll
        for (int q = 0; q < 2; ++q) {
            const int idx = q * 256 + tid;
            mwords[idx] = bb[(size_t)(n0 + (idx >> 2)) * (N_ / 32) + (m0 >> 5) + (idx & 3)];
        }
    }

    int aoff[4], boff[4];
#pragma unroll
    for (int i = 0; i < 4; ++i) {
        const int ra = wr * 64 + i * 16 + l15;
        aoff[i] = ra * 32 + (((kg + (ra >> 1)) & 3) << 3);
        const int rb = wc * 64 + i * 16 + l15;
        boff[i] = rb * 32 + (((kg + (rb >> 1)) & 3) << 3);
    }
    const f32x4 zero = {0.f, 0.f, 0.f, 0.f};
    f32x4 acc[4][4];
#pragma unroll
    for (int i = 0; i < 4; ++i)
#pragma unroll
        for (int j = 0; j < 4; ++j) acc[i][j] = zero;

    for (int kt = 0; kt < K; kt += 32) {
        __syncthreads();
#pragma unroll
        for (int q = 0; q < 2; ++q) {
            const int c = q * 256 + tid;
            const int r = c >> 2;
            const int kc = ((c & 3) - (r >> 1)) & 3;
            const short* ga = A + (size_t)(m0 + r) * K + kt + kc * 8;
            __builtin_amdgcn_global_load_lds((const AS1 void*)ga,
                (AS3 void*)(lsA + (q * 256 + wid * 64) * 8), 16, 0, 0);
            const short* gb = Bm + (size_t)(n0 + r) * K + kt + kc * 8;
            __builtin_amdgcn_global_load_lds((const AS1 void*)gb,
                (AS3 void*)(lsB + (q * 256 + wid * 64) * 8), 16, 0, 0);
        }
        __syncthreads();
        bf16x8 fa[4], fb[4];
#pragma unroll
        for (int i = 0; i < 4; ++i) fa[i] = *(const bf16x8*)(lsA + aoff[i]);
#pragma unroll
        for (int j = 0; j < 4; ++j) fb[j] = *(const bf16x8*)(lsB + boff[j]);
#pragma unroll
        for (int i = 0; i < 4; ++i)
#pragma unroll
            for (int j = 0; j < 4; ++j)
                acc[i][j] = __builtin_amdgcn_mfma_f32_16x16x32_bf16(fa[i], fb[j], acc[i][j], 0, 0, 0);
    }

    __syncthreads();  // all fragment reads done; ls is now free for repack

    float evsum[4] = {0.f, 0.f, 0.f, 0.f};

    if (MODE == M_BF16 || MODE == M_SCALE) {
        unsigned short* C = (unsigned short*)Cv + (size_t)b * sC;
#pragma unroll
        for (int h = 0; h < 2; ++h) {
            if (wr == h) {
#pragma unroll
                for (int i = 0; i < 4; ++i)
#pragma unroll
                    for (int j = 0; j < 4; ++j)
#pragma unroll
                        for (int r = 0; r < 4; ++r) {
                            const int rl = i * 16 + kg * 4 + r;        // 0..63
                            const int cl = wc * 64 + j * 16 + l15;     // 0..127
                            float v = acc[i][j][r];
                            if (MODE == M_SCALE) v *= scale;
                            if (MASKSUM) {
                                const int rowfull = h * 64 + rl;
                                const uint32_t bit =
                                    (mwords[cl * 4 + (rowfull >> 5)] >> (rowfull & 31)) & 1u;
                                if (!bit) v = INF_SUB;
                            }
                            const unsigned short hv = f2bf(v);
                            ls[rl * 128 + cl] = (short)hv;
                            if (MASKSUM) evsum[j] += __expf(bf2f(hv));
                        }
            }
            __syncthreads();
#pragma unroll
            for (int si = 0; si < 4; ++si) {
                const int row = (tid >> 4) + si * 16;   // 0..63
                const int col = (tid & 15) * 8;         // 0..120
                us8 val = *(us8*)&ls[row * 128 + col];
                *(us8*)&C[(size_t)(m0 + h * 64 + row) * ldc + n0 + col] = val;
            }
            __syncthreads();
        }
        if (MASKSUM) {
#pragma unroll
            for (int j = 0; j < 4; ++j) {
                float cs = evsum[j];
                cs += __shfl_xor(cs, 16, 64);
                cs += __shfl_xor(cs, 32, 64);
                if (kg == 0)
                    atomicAdd(&lsum[(size_t)b * E_ + n0 + wc * 64 + j * 16 + l15], cs);
            }
        }
    } else {
        // f32 repack path (M_ADD: bf16 out with bf16 addend; M_F32: f32 out)
        float* lsF = (float*)ls;
#pragma unroll
        for (int h = 0; h < 4; ++h) {
            if (wr == (h >> 1)) {
#pragma unroll
                for (int ii = 0; ii < 2; ++ii) {
                    const int i = (h & 1) * 2 + ii;
#pragma unroll
                    for (int j = 0; j < 4; ++j)
#pragma unroll
                        for (int r = 0; r < 4; ++r) {
                            const int rl = ii * 16 + kg * 4 + r;      // 0..31
                            const int cl = wc * 64 + j * 16 + l15;
                            lsF[rl * 128 + cl] = acc[i][j][r];
                        }
                }
            }
            __syncthreads();
#pragma unroll
            for (int si = 0; si < 4; ++si) {
                const int row = (tid >> 5) + si * 8;    // 0..31
                const int colb = (tid & 31) * 4;        // 0..124
                float4 v = *(float4*)&lsF[row * 128 + colb];
                const int grow = m0 + h * 32 + row;
                if (MODE == M_ADD) {
                    const ushort4 a = *(const ushort4*)&Add[(size_t)b * sC +
                                                            (size_t)grow * ldc + n0 + colb];
                    ushort4 o = make_ushort4(f2bf(v.x + bf2f(a.x)), f2bf(v.y + bf2f(a.y)),
                                             f2bf(v.z + bf2f(a.z)), f2bf(v.w + bf2f(a.w)));
                    *(ushort4*)&((unsigned short*)Cv)[(size_t)b * sC +
                                                      (size_t)grow * ldc + n0 + colb] = o;
                } else {
                    *(float4*)&((float*)Cv)[(size_t)b * sC +
                                            (size_t)grow * ldc + n0 + colb] = v;
                }
            }
            __syncthreads();
        }
    }
}

// ---------------------------------------------------------------------------
extern "C" void kernel_launch(void* const* d_in, const int* in_sizes, int n_in,
                              void* d_out, int out_size, void* d_ws, size_t ws_size,
                              hipStream_t stream) {
    const float* hidden = (const float*)d_in[0];    // [B,N,D]
    const int* ht = (const int*)d_in[1];            // [B,E,N]
    const float* edge_emb = (const float*)d_in[2];  // [B,E,D]
    const float* wnk = (const float*)d_in[3];       // [D,D]
    const float* wek = (const float*)d_in[4];       // [D,D]
    const float* gamma = (const float*)d_in[5];     // [D]
    const float* beta = (const float*)d_in[6];      // [D]
    float* out = (float*)d_out;                     // [B,N,D]
    (void)in_sizes; (void)n_in; (void)out_size; (void)ws_size;

    char* w = (char*)d_ws;
    unsigned short* SP = (unsigned short*)w;         w += (size_t)B_ * E_ * N_ * 2;  // 134MB (S1/P1 then S2T/P2T)
    unsigned short* hidden_bf = (unsigned short*)w;  w += (size_t)B_ * N_ * D_ * 2;
    unsigned short* hiddenT_bf = (unsigned short*)w; w += (size_t)B_ * D_ * N_ * 2;
    unsigned short* node_k_bf = (unsigned short*)w;  w += (size_t)B_ * N_ * D_ * 2;
    unsigned short* eln_bf = (unsigned short*)w;     w += (size_t)B_ * E_ * D_ * 2;
    unsigned short* edge_h_bf = (unsigned short*)w;  w += (size_t)B_ * E_ * D_ * 2;
    unsigned short* edge_hT_bf = (unsigned short*)w; w += (size_t)B_ * D_ * E_ * 2;
    unsigned short* edge_k_bf = (unsigned short*)w;  w += (size_t)B_ * E_ * D_ * 2;
    uint32_t* bits = (uint32_t*)w;                   w += (size_t)B_ * E_ * (N_ / 32) * 4;
    float* lsum = (float*)w;                         w += (size_t)B_ * E_ * 4;       // 64KB
    unsigned short* wnkT = (unsigned short*)w;       w += (size_t)D_ * D_ * 2;
    unsigned short* wekT = (unsigned short*)w;       w += (size_t)D_ * D_ * 2;

    const float scale = 0.0625f;  // 1/sqrt(256)

    // prep
    prep_hidden<<<dim3(D_ / 64, N_ / 64, B_), 256, 0, stream>>>(hidden, hidden_bf, hiddenT_bf);
    cast_wT<<<D_ * D_ / 256, 256, 0, stream>>>(wnk, wnkT);
    cast_wT<<<D_ * D_ / 256, 256, 0, stream>>>(wek, wekT);
    ln_kernel<<<B_ * E_, 256, 0, stream>>>(edge_emb, gamma, beta, eln_bf);
    pack_mask<<<B_ * E_, 256, 0, stream>>>(ht, bits);

    // node_k = hidden @ wnk
    mfma_gemm_nt<M_BF16, 0><<<dim3(D_ / 128, (B_ * N_) / 128, 1), 256, 0, stream>>>(
        (const short*)hidden_bf, (const short*)wnkT, node_k_bf, nullptr, nullptr, nullptr,
        D_, D_, 0, 0, 0, 1.f);
    // S1[e,n] = eln . node_k * scale   ([E,N], raw scores)
    mfma_gemm_nt<M_SCALE, 0><<<dim3(N_ / 128, E_ / 128, B_), 256, 0, stream>>>(
        (const short*)eln_bf, (const short*)node_k_bf, SP, nullptr, nullptr, nullptr,
        D_, N_, (size_t)E_ * D_, (size_t)N_ * D_, (size_t)E_ * N_, scale);
    // stage-1 masked softmax (row-wise)
    softmax_bits<<<B_ * E_, 256, 0, stream>>>(SP, bits);
    // edge_h = P1 @ hidden + eln
    mfma_gemm_nt<M_ADD, 0><<<dim3(D_ / 128, E_ / 128, B_), 256, 0, stream>>>(
        (const short*)SP, (const short*)hiddenT_bf, edge_h_bf, eln_bf, nullptr, nullptr,
        N_, D_, (size_t)E_ * N_, (size_t)D_ * N_, (size_t)E_ * D_, 1.f);
    transpose_bf<<<dim3(D_ / 64, E_ / 64, B_), 256, 0, stream>>>(
        edge_h_bf, edge_hT_bf, E_, D_, (size_t)E_ * D_, (size_t)D_ * E_);
    // edge_k = edge_h @ wek
    mfma_gemm_nt<M_BF16, 0><<<dim3(D_ / 128, (B_ * E_) / 128, 1), 256, 0, stream>>>(
        (const short*)edge_h_bf, (const short*)wekT, edge_k_bf, nullptr, nullptr, nullptr,
        D_, D_, 0, 0, 0, 1.f);
    // S2T[n,e] = node_k . edge_k * scale, masked; col exp-sums -> lsum (atomics)
    hipMemsetAsync(lsum, 0, (size_t)B_ * E_ * 4, stream);
    mfma_gemm_nt<M_SCALE, 1><<<dim3(E_ / 128, N_ / 128, B_), 256, 0, stream>>>(
        (const short*)node_k_bf, (const short*)edge_k_bf, SP, nullptr, bits, lsum,
        D_, E_, (size_t)N_ * D_, (size_t)E_ * D_, (size_t)N_ * E_, scale);
    // P2T = exp(S2T) / lsum[e]
    apply_colsoftmax<<<dim3(1, N_ / 32, B_), 256, 0, stream>>>(SP, lsum);
    // out = P2^T @ edge_h   (A = P2T [N,E], B = edge_hT [D,E])
    mfma_gemm_nt<M_F32, 0><<<dim3(D_ / 128, N_ / 128, B_), 256, 0, stream>>>(
        (const short*)SP, (const short*)edge_hT_bf, out, nullptr, nullptr, nullptr,
        E_, D_, (size_t)N_ * E_, (size_t)D_ * E_, (size_t)N_ * D_, 1.f);
}

// Round 4
// 920.189 us; speedup vs baseline: 2.8579x; 1.0058x over previous
//
#include <hip/hip_runtime.h>
#include <hip/hip_bf16.h>
#include <stdint.h>

// R4: exp + softmax-denominator fused into the score GEMM epilogues (row-sum
// atomics for stage 1, col-sum for stage 2); both softmax kernels deleted.
// Normalization factored out: 1/rsum applied in PV-reduce, 1/lsum folded into
// the V operand of the final GEMM. PV split-K=2 into f32 slabs (512 blocks).

#define B_ 8
#define N_ 4096
#define E_ 2048
#define D_ 256

typedef short bf16x8 __attribute__((ext_vector_type(8)));
typedef float f32x4 __attribute__((ext_vector_type(4)));
typedef unsigned short us8 __attribute__((ext_vector_type(8)));

#define AS1 __attribute__((address_space(1)))
#define AS3 __attribute__((address_space(3)))

__device__ __forceinline__ unsigned short f2bf(float f) {
    union { float f; unsigned int u; } v; v.f = f;
    unsigned int r = v.u + 0x7fffu + ((v.u >> 16) & 1u);
    return (unsigned short)(r >> 16);
}
__device__ __forceinline__ float bf2f(unsigned short h) {
    union { unsigned int u; float f; } v; v.u = ((unsigned int)h) << 16;
    return v.f;
}
__device__ __forceinline__ float waveReduceSum(float v) {
#pragma unroll
    for (int o = 32; o > 0; o >>= 1) v += __shfl_xor(v, o, 64);
    return v;
}

// ---------------- LayerNorm over D=256 -> bf16 ------------------------------
__global__ __launch_bounds__(256) void ln_kernel(const float* __restrict__ x,
                                                 const float* __restrict__ gamma,
                                                 const float* __restrict__ beta,
                                                 unsigned short* __restrict__ yb) {
    __shared__ float red[8];
    const int row = blockIdx.x;
    const int t = threadIdx.x;
    const int lane = t & 63, wid = t >> 6;
    const float v = x[(size_t)row * D_ + t];
    float s = waveReduceSum(v);
    if (lane == 0) red[wid] = s;
    __syncthreads();
    const float mu = (red[0] + red[1] + red[2] + red[3]) * (1.0f / D_);
    const float d = v - mu;
    float s2 = waveReduceSum(d * d);
    if (lane == 0) red[4 + wid] = s2;
    __syncthreads();
    const float var = (red[4] + red[5] + red[6] + red[7]) * (1.0f / D_);
    yb[(size_t)row * D_ + t] = f2bf(gamma[t] * d * rsqrtf(var + 1e-5f) + beta[t]);
}

// ---------------- pack ht -> bitmask: bits[b][e][n>>5] bit (n&31) -----------
__global__ __launch_bounds__(256) void pack_mask(const int* __restrict__ ht,
                                                 uint32_t* __restrict__ bits) {
    const int row = blockIdx.x;
    const int t = threadIdx.x, wid = t >> 6, lane = t & 63;
    const int* hrow = ht + (size_t)row * N_;
    uint32_t* brow = bits + (size_t)row * (N_ / 32);
#pragma unroll
    for (int i = 0; i < 16; ++i) {
        const int c = wid * 16 + i;
        const int v = hrow[c * 64 + lane];
        unsigned long long m = __ballot(v > 0);
        if (lane == 0) {
            brow[c * 2] = (uint32_t)m;
            brow[c * 2 + 1] = (uint32_t)(m >> 32);
        }
    }
}

// ---------------- fp32 [N,D] -> bf16 [N,D] + bf16 [D,N] ---------------------
__global__ __launch_bounds__(256) void prep_hidden(const float* __restrict__ in,
                                                   unsigned short* __restrict__ hb,
                                                   unsigned short* __restrict__ hT) {
    __shared__ unsigned short tile[64][65];
    const int b = blockIdx.z;
    in += (size_t)b * N_ * D_;
    hb += (size_t)b * N_ * D_;
    hT += (size_t)b * D_ * N_;
    const int n0 = blockIdx.y * 64, d0 = blockIdx.x * 64;
    const int t = threadIdx.x;
    const int tr = t >> 4, tc = (t & 15) * 4;
#pragma unroll
    for (int q = 0; q < 4; ++q) {
        const int rr = q * 16 + tr;
        const float4 f = *(const float4*)&in[(size_t)(n0 + rr) * D_ + d0 + tc];
        unsigned short h0 = f2bf(f.x), h1 = f2bf(f.y), h2 = f2bf(f.z), h3 = f2bf(f.w);
        *(ushort4*)&hb[(size_t)(n0 + rr) * D_ + d0 + tc] = make_ushort4(h0, h1, h2, h3);
        tile[rr][tc + 0] = h0; tile[rr][tc + 1] = h1;
        tile[rr][tc + 2] = h2; tile[rr][tc + 3] = h3;
    }
    __syncthreads();
#pragma unroll
    for (int q = 0; q < 4; ++q) {
        const int cc = q * 16 + tr;
        ushort4 o = make_ushort4(tile[tc + 0][cc], tile[tc + 1][cc],
                                 tile[tc + 2][cc], tile[tc + 3][cc]);
        *(ushort4*)&hT[(size_t)(d0 + cc) * N_ + n0 + tc] = o;
    }
}

// ---------------- tiny: w[D,D] f32 -> wT[D,D] bf16 --------------------------
__global__ __launch_bounds__(256) void cast_wT(const float* __restrict__ w,
                                               unsigned short* __restrict__ wT) {
    const int gid = blockIdx.x * 256 + threadIdx.x;
    const int i = gid >> 8, j = gid & 255;
    wT[j * D_ + i] = f2bf(w[i * D_ + j]);
}

// ---- PV slab reduce: edge_h = (slab0+slab1)/rsum + eln; also f32 [D,E] T ---
__global__ __launch_bounds__(256) void reduce_pv(const float* __restrict__ slab,
                                                 const unsigned short* __restrict__ eln,
                                                 const float* __restrict__ rsum,
                                                 unsigned short* __restrict__ eh,
                                                 float* __restrict__ ehT) {
    __shared__ float tile[64][65];
    const int b = blockIdx.z;
    const float* s0 = slab + (size_t)(b * 2) * E_ * D_;
    const float* s1 = slab + (size_t)(b * 2 + 1) * E_ * D_;
    const int e0 = blockIdx.y * 64, d0 = blockIdx.x * 64;
    const int t = threadIdx.x;
    const int tr = t >> 4, tc = (t & 15) * 4;
#pragma unroll
    for (int q = 0; q < 4; ++q) {
        const int rr = q * 16 + tr;
        const int row = e0 + rr;
        const float4 v0 = *(const float4*)&s0[(size_t)row * D_ + d0 + tc];
        const float4 v1 = *(const float4*)&s1[(size_t)row * D_ + d0 + tc];
        const float inv = 1.0f / rsum[(size_t)b * E_ + row];
        const ushort4 el = *(const ushort4*)&eln[(size_t)b * E_ * D_ + (size_t)row * D_ + d0 + tc];
        const float x0 = (v0.x + v1.x) * inv + bf2f(el.x);
        const float x1 = (v0.y + v1.y) * inv + bf2f(el.y);
        const float x2 = (v0.z + v1.z) * inv + bf2f(el.z);
        const float x3 = (v0.w + v1.w) * inv + bf2f(el.w);
        *(ushort4*)&eh[(size_t)b * E_ * D_ + (size_t)row * D_ + d0 + tc] =
            make_ushort4(f2bf(x0), f2bf(x1), f2bf(x2), f2bf(x3));
        tile[rr][tc + 0] = x0; tile[rr][tc + 1] = x1;
        tile[rr][tc + 2] = x2; tile[rr][tc + 3] = x3;
    }
    __syncthreads();
#pragma unroll
    for (int q = 0; q < 4; ++q) {
        const int cc = q * 16 + tr;
        float4 o = make_float4(tile[tc + 0][cc], tile[tc + 1][cc],
                               tile[tc + 2][cc], tile[tc + 3][cc]);
        *(float4*)&ehT[(size_t)b * D_ * E_ + (size_t)(d0 + cc) * E_ + e0 + tc] = o;
    }
}

// ---- edge_hsT[d,e] = ehT[d,e] / lsum[e]  (f32 in, bf16 out, [B,D,E]) -------
__global__ __launch_bounds__(256) void scale_ehT(const float* __restrict__ ehT,
                                                 const float* __restrict__ lsum,
                                                 unsigned short* __restrict__ ehs) {
    const size_t base = ((size_t)blockIdx.x * 256 + threadIdx.x) * 8;
    const int b = (int)(base / ((size_t)D_ * E_));
    const int e = (int)(base % E_);
    const float4 f0 = *(const float4*)&ehT[base];
    const float4 f1 = *(const float4*)&ehT[base + 4];
    const float4 l0 = *(const float4*)&lsum[(size_t)b * E_ + e];
    const float4 l1 = *(const float4*)&lsum[(size_t)b * E_ + e + 4];
    us8 o;
    o[0] = f2bf(f0.x / l0.x); o[1] = f2bf(f0.y / l0.y);
    o[2] = f2bf(f0.z / l0.z); o[3] = f2bf(f0.w / l0.w);
    o[4] = f2bf(f1.x / l1.x); o[5] = f2bf(f1.y / l1.y);
    o[6] = f2bf(f1.z / l1.z); o[7] = f2bf(f1.w / l1.w);
    *(us8*)&ehs[base] = o;
}

// ---------------- MFMA NT GEMM: C[m,n] = sum_k A[m,k]*Bt[n,k] ---------------
// 128x128 tile, BK=32, global_load_lds w=16, swizzled LDS, LDS-repack epilogue.
#define M_BF16 0  // bf16 raw out
#define M_EXP 1   // bf16 out = exp(mask(acc*scale)); SUM picks row/col denominators
#define M_F32 2   // f32 raw out
#define S_NONE 0
#define S_ROW 1
#define S_COL 2

template <int MODE, int SUM, int SPLIT>
__global__ __launch_bounds__(256) void mfma_gemm_nt(
        const short* __restrict__ A, const short* __restrict__ Bm,
        void* __restrict__ Cv, const uint32_t* __restrict__ bits,
        float* __restrict__ sums,
        int K, int ldc, size_t sA, size_t sB, size_t sC, float scale) {
    __shared__ __align__(16) short ls[8192];  // 16 KB staging, reused by repack
    __shared__ uint32_t mwords[512];
    short* lsA = ls;
    short* lsB = ls + 4096;
    const int zb = blockIdx.z;
    const int b = SPLIT ? (zb >> 1) : zb;
    A += (size_t)b * sA;
    Bm += (size_t)b * sB;
    const int m0 = blockIdx.y * 128, n0 = blockIdx.x * 128;
    const int tid = threadIdx.x, wid = tid >> 6, lane = tid & 63;
    const int l15 = lane & 15, kg = lane >> 4;
    const int wr = wid >> 1, wc = wid & 1;

    if (SUM != S_NONE) {
        const uint32_t* bb = bits + (size_t)b * E_ * (N_ / 32);
#pragma unroll
        for (int q = 0; q < 2; ++q) {
            const int idx = q * 256 + tid;
            mwords[idx] = (SUM == S_ROW)
                ? bb[(size_t)(m0 + (idx >> 2)) * (N_ / 32) + (n0 >> 5) + (idx & 3)]
                : bb[(size_t)(n0 + (idx >> 2)) * (N_ / 32) + (m0 >> 5) + (idx & 3)];
        }
    }

    int aoff[4], boff[4];
#pragma unroll
    for (int i = 0; i < 4; ++i) {
        const int ra = wr * 64 + i * 16 + l15;
        aoff[i] = ra * 32 + (((kg + (ra >> 1)) & 3) << 3);
        const int rb = wc * 64 + i * 16 + l15;
        boff[i] = rb * 32 + (((kg + (rb >> 1)) & 3) << 3);
    }
    const f32x4 zero = {0.f, 0.f, 0.f, 0.f};
    f32x4 acc[4][4];
#pragma unroll
    for (int i = 0; i < 4; ++i)
#pragma unroll
        for (int j = 0; j < 4; ++j) acc[i][j] = zero;

    const int kt0 = SPLIT ? (zb & 1) * (K >> 1) : 0;
    const int ktE = SPLIT ? kt0 + (K >> 1) : K;
    for (int kt = kt0; kt < ktE; kt += 32) {
        __syncthreads();
#pragma unroll
        for (int q = 0; q < 2; ++q) {
            const int c = q * 256 + tid;
            const int r = c >> 2;
            const int kc = ((c & 3) - (r >> 1)) & 3;
            const short* ga = A + (size_t)(m0 + r) * K + kt + kc * 8;
            __builtin_amdgcn_global_load_lds((const AS1 void*)ga,
                (AS3 void*)(lsA + (q * 256 + wid * 64) * 8), 16, 0, 0);
            const short* gb = Bm + (size_t)(n0 + r) * K + kt + kc * 8;
            __builtin_amdgcn_global_load_lds((const AS1 void*)gb,
                (AS3 void*)(lsB + (q * 256 + wid * 64) * 8), 16, 0, 0);
        }
        __syncthreads();
        bf16x8 fa[4], fb[4];
#pragma unroll
        for (int i = 0; i < 4; ++i) fa[i] = *(const bf16x8*)(lsA + aoff[i]);
#pragma unroll
        for (int j = 0; j < 4; ++j) fb[j] = *(const bf16x8*)(lsB + boff[j]);
#pragma unroll
        for (int i = 0; i < 4; ++i)
#pragma unroll
            for (int j = 0; j < 4; ++j)
                acc[i][j] = __builtin_amdgcn_mfma_f32_16x16x32_bf16(fa[i], fb[j], acc[i][j], 0, 0, 0);
    }

    __syncthreads();  // fragment reads done; ls free for repack

    if (MODE == M_F32) {
        float* C = (float*)Cv + (SPLIT ? (size_t)zb * sC : (size_t)b * sC);
        float* lsF = (float*)ls;
#pragma unroll
        for (int h = 0; h < 4; ++h) {
            if (wr == (h >> 1)) {
#pragma unroll
                for (int ii = 0; ii < 2; ++ii) {
                    const int i = (h & 1) * 2 + ii;
#pragma unroll
                    for (int j = 0; j < 4; ++j)
#pragma unroll
                        for (int r = 0; r < 4; ++r) {
                            const int rl = ii * 16 + kg * 4 + r;
                            const int cl = wc * 64 + j * 16 + l15;
                            lsF[rl * 128 + cl] = acc[i][j][r];
                        }
                }
            }
            __syncthreads();
#pragma unroll
            for (int si = 0; si < 4; ++si) {
                const int row = (tid >> 5) + si * 8;
                const int colb = (tid & 31) * 4;
                float4 v = *(float4*)&lsF[row * 128 + colb];
                *(float4*)&C[(size_t)(m0 + h * 32 + row) * ldc + n0 + colb] = v;
            }
            __syncthreads();
        }
    } else {
        unsigned short* C = (unsigned short*)Cv + (size_t)b * sC;
        float evsum[4] = {0.f, 0.f, 0.f, 0.f};
#pragma unroll
        for (int h = 0; h < 2; ++h) {
            if (wr == h) {
                float rpart[16];
                if (SUM == S_ROW)
#pragma unroll
                    for (int q = 0; q < 16; ++q) rpart[q] = 0.f;
#pragma unroll
                for (int i = 0; i < 4; ++i)
#pragma unroll
                    for (int j = 0; j < 4; ++j)
#pragma unroll
                        for (int r = 0; r < 4; ++r) {
                            const int rl = i * 16 + kg * 4 + r;
                            const int cl = wc * 64 + j * 16 + l15;
                            float v = acc[i][j][r];
                            if (MODE == M_EXP) {
                                v *= scale;
                                const int rowfull = h * 64 + rl;
                                const uint32_t bit = (SUM == S_ROW)
                                    ? (mwords[rowfull * 4 + (cl >> 5)] >> (cl & 31)) & 1u
                                    : (mwords[cl * 4 + (rowfull >> 5)] >> (rowfull & 31)) & 1u;
                                v = bit ? __expf(v) : 0.f;
                            }
                            const unsigned short hv = f2bf(v);
                            ls[rl * 128 + cl] = (short)hv;
                            if (MODE == M_EXP) {
                                const float pv = bf2f(hv);
                                if (SUM == S_ROW) rpart[i * 4 + r] += pv;
                                else evsum[j] += pv;
                            }
                        }
                if (MODE == M_EXP && SUM == S_ROW) {
#pragma unroll
                    for (int i = 0; i < 4; ++i)
#pragma unroll
                        for (int r = 0; r < 4; ++r) {
                            float s = rpart[i * 4 + r];
                            s += __shfl_xor(s, 1, 64);
                            s += __shfl_xor(s, 2, 64);
                            s += __shfl_xor(s, 4, 64);
                            s += __shfl_xor(s, 8, 64);
                            if (l15 == 0)
                                atomicAdd(&sums[(size_t)b * E_ + m0 + h * 64 + i * 16 + kg * 4 + r], s);
                        }
                }
            }
            __syncthreads();
#pragma unroll
            for (int si = 0; si < 4; ++si) {
                const int row = (tid >> 4) + si * 16;
                const int col = (tid & 15) * 8;
                us8 val = *(us8*)&ls[row * 128 + col];
                *(us8*)&C[(size_t)(m0 + h * 64 + row) * ldc + n0 + col] = val;
            }
            __syncthreads();
        }
        if (MODE == M_EXP && SUM == S_COL) {
#pragma unroll
            for (int j = 0; j < 4; ++j) {
                float cs = evsum[j];
                cs += __shfl_xor(cs, 16, 64);
                cs += __shfl_xor(cs, 32, 64);
                if (kg == 0)
                    atomicAdd(&sums[(size_t)b * E_ + n0 + wc * 64 + j * 16 + l15], cs);
            }
        }
    }
}

// ---------------------------------------------------------------------------
extern "C" void kernel_launch(void* const* d_in, const int* in_sizes, int n_in,
                              void* d_out, int out_size, void* d_ws, size_t ws_size,
                              hipStream_t stream) {
    const float* hidden = (const float*)d_in[0];    // [B,N,D]
    const int* ht = (const int*)d_in[1];            // [B,E,N]
    const float* edge_emb = (const float*)d_in[2];  // [B,E,D]
    const float* wnk = (const float*)d_in[3];       // [D,D]
    const float* wek = (const float*)d_in[4];       // [D,D]
    const float* gamma = (const float*)d_in[5];     // [D]
    const float* beta = (const float*)d_in[6];      // [D]
    float* out = (float*)d_out;                     // [B,N,D]
    (void)in_sizes; (void)n_in; (void)out_size; (void)ws_size;

    char* w = (char*)d_ws;
    unsigned short* SP = (unsigned short*)w;         w += (size_t)B_ * E_ * N_ * 2;   // 134MB (ex1 [E,N], then ex2T [N,E])
    unsigned short* hidden_bf = (unsigned short*)w;  w += (size_t)B_ * N_ * D_ * 2;
    unsigned short* hiddenT_bf = (unsigned short*)w; w += (size_t)B_ * D_ * N_ * 2;
    unsigned short* node_k_bf = (unsigned short*)w;  w += (size_t)B_ * N_ * D_ * 2;
    unsigned short* eln_bf = (unsigned short*)w;     w += (size_t)B_ * E_ * D_ * 2;
    unsigned short* edge_h_bf = (unsigned short*)w;  w += (size_t)B_ * E_ * D_ * 2;
    float* ehT_f32 = (float*)w;                      w += (size_t)B_ * D_ * E_ * 4;   // 33.6MB
    unsigned short* ehsT_bf = (unsigned short*)w;    w += (size_t)B_ * D_ * E_ * 2;
    unsigned short* edge_k_bf = (unsigned short*)w;  w += (size_t)B_ * E_ * D_ * 2;
    float* slabs = (float*)w;                        w += (size_t)B_ * 2 * E_ * D_ * 4; // 33.6MB
    uint32_t* bits = (uint32_t*)w;                   w += (size_t)B_ * E_ * (N_ / 32) * 4;
    float* rsum = (float*)w;                         w += (size_t)B_ * E_ * 4;
    float* lsum = (float*)w;                         w += (size_t)B_ * E_ * 4;
    unsigned short* wnkT = (unsigned short*)w;       w += (size_t)D_ * D_ * 2;
    unsigned short* wekT = (unsigned short*)w;       w += (size_t)D_ * D_ * 2;

    const float scale = 0.0625f;  // 1/sqrt(256)

    // prep
    prep_hidden<<<dim3(D_ / 64, N_ / 64, B_), 256, 0, stream>>>(hidden, hidden_bf, hiddenT_bf);
    cast_wT<<<D_ * D_ / 256, 256, 0, stream>>>(wnk, wnkT);
    cast_wT<<<D_ * D_ / 256, 256, 0, stream>>>(wek, wekT);
    ln_kernel<<<B_ * E_, 256, 0, stream>>>(edge_emb, gamma, beta, eln_bf);
    pack_mask<<<B_ * E_, 256, 0, stream>>>(ht, bits);
    hipMemsetAsync(rsum, 0, (size_t)B_ * E_ * 8, stream);  // rsum + lsum (adjacent)

    // node_k = hidden @ wnk
    mfma_gemm_nt<M_BF16, S_NONE, 0><<<dim3(D_ / 128, (B_ * N_) / 128, 1), 256, 0, stream>>>(
        (const short*)hidden_bf, (const short*)wnkT, node_k_bf, nullptr, nullptr,
        D_, D_, 0, 0, 0, 1.f);
    // ex1[e,n] = exp(mask(eln . node_k * scale)); rsum[e] += (row sums)
    mfma_gemm_nt<M_EXP, S_ROW, 0><<<dim3(N_ / 128, E_ / 128, B_), 256, 0, stream>>>(
        (const short*)eln_bf, (const short*)node_k_bf, SP, bits, rsum,
        D_, N_, (size_t)E_ * D_, (size_t)N_ * D_, (size_t)E_ * N_, scale);
    // PV slabs: slab[b*2+s][e,d] = sum_{n in half s} ex1[e,n]*hidden[n,d]
    mfma_gemm_nt<M_F32, S_NONE, 1><<<dim3(D_ / 128, E_ / 128, B_ * 2), 256, 0, stream>>>(
        (const short*)SP, (const short*)hiddenT_bf, slabs, nullptr, nullptr,
        N_, D_, (size_t)E_ * N_, (size_t)D_ * N_, (size_t)E_ * D_, 1.f);
    // edge_h = (slab0+slab1)/rsum + eln  -> bf16 [E,D] and f32 [D,E]
    reduce_pv<<<dim3(D_ / 64, E_ / 64, B_), 256, 0, stream>>>(
        slabs, eln_bf, rsum, edge_h_bf, ehT_f32);
    // edge_k = edge_h @ wek
    mfma_gemm_nt<M_BF16, S_NONE, 0><<<dim3(D_ / 128, (B_ * E_) / 128, 1), 256, 0, stream>>>(
        (const short*)edge_h_bf, (const short*)wekT, edge_k_bf, nullptr, nullptr,
        D_, D_, 0, 0, 0, 1.f);
    // ex2T[n,e] = exp(mask(node_k . edge_k * scale)); lsum[e] += (col sums)
    mfma_gemm_nt<M_EXP, S_COL, 0><<<dim3(E_ / 128, N_ / 128, B_), 256, 0, stream>>>(
        (const short*)node_k_bf, (const short*)edge_k_bf, SP, bits, lsum,
        D_, E_, (size_t)N_ * D_, (size_t)E_ * D_, (size_t)N_ * E_, scale);
    // edge_hs[d,e] = ehT/lsum[e]
    scale_ehT<<<(B_ * D_ * E_) / (256 * 8), 256, 0, stream>>>(ehT_f32, lsum, ehsT_bf);
    // out[n,d] = sum_e ex2T[n,e] * edge_hs[d,e]
    mfma_gemm_nt<M_F32, S_NONE, 0><<<dim3(D_ / 128, N_ / 128, B_), 256, 0, stream>>>(
        (const short*)SP, (const short*)ehsT_bf, out, nullptr, nullptr,
        E_, D_, (size_t)N_ * E_, (size_t)D_ * E_, (size_t)N_ * D_, 1.f);
}

// Round 5
// 868.122 us; speedup vs baseline: 3.0293x; 1.0600x over previous
//
#include <hip/hip_runtime.h>
#include <hip/hip_bf16.h>
#include <stdint.h>

// R5: score GEMMs store RAW-masked bf16 scores (cheap single-phase repack,
// conflict-free LDS stride, b64 mask reads). exp() moved into the consuming
// GEMMs' A-operand staging path (VGPR->LDS), where it overlaps MFMA. PV
// computes rsum in-register (no S1 sum atomics); lsum via light colsum pass.

#define B_ 8
#define N_ 4096
#define E_ 2048
#define D_ 256
#define INF_SUB (-9.0e15f)

typedef short bf16x8 __attribute__((ext_vector_type(8)));
typedef float f32x4 __attribute__((ext_vector_type(4)));
typedef unsigned short us8 __attribute__((ext_vector_type(8)));

#define AS1 __attribute__((address_space(1)))
#define AS3 __attribute__((address_space(3)))

__device__ __forceinline__ unsigned short f2bf(float f) {
    union { float f; unsigned int u; } v; v.f = f;
    unsigned int r = v.u + 0x7fffu + ((v.u >> 16) & 1u);
    return (unsigned short)(r >> 16);
}
__device__ __forceinline__ float bf2f(unsigned short h) {
    union { unsigned int u; float f; } v; v.u = ((unsigned int)h) << 16;
    return v.f;
}
__device__ __forceinline__ float waveReduceSum(float v) {
#pragma unroll
    for (int o = 32; o > 0; o >>= 1) v += __shfl_xor(v, o, 64);
    return v;
}

// ---------------- LayerNorm over D=256 -> bf16 ------------------------------
__global__ __launch_bounds__(256) void ln_kernel(const float* __restrict__ x,
                                                 const float* __restrict__ gamma,
                                                 const float* __restrict__ beta,
                                                 unsigned short* __restrict__ yb) {
    __shared__ float red[8];
    const int row = blockIdx.x;
    const int t = threadIdx.x;
    const int lane = t & 63, wid = t >> 6;
    const float v = x[(size_t)row * D_ + t];
    float s = waveReduceSum(v);
    if (lane == 0) red[wid] = s;
    __syncthreads();
    const float mu = (red[0] + red[1] + red[2] + red[3]) * (1.0f / D_);
    const float d = v - mu;
    float s2 = waveReduceSum(d * d);
    if (lane == 0) red[4 + wid] = s2;
    __syncthreads();
    const float var = (red[4] + red[5] + red[6] + red[7]) * (1.0f / D_);
    yb[(size_t)row * D_ + t] = f2bf(gamma[t] * d * rsqrtf(var + 1e-5f) + beta[t]);
}

// ---------------- pack ht -> bitmask: bits[b][e][n>>5] bit (n&31) -----------
__global__ __launch_bounds__(256) void pack_mask(const int* __restrict__ ht,
                                                 uint32_t* __restrict__ bits) {
    const int row = blockIdx.x;
    const int t = threadIdx.x, wid = t >> 6, lane = t & 63;
    const int* hrow = ht + (size_t)row * N_;
    uint32_t* brow = bits + (size_t)row * (N_ / 32);
#pragma unroll
    for (int i = 0; i < 16; ++i) {
        const int c = wid * 16 + i;
        const int v = hrow[c * 64 + lane];
        unsigned long long m = __ballot(v > 0);
        if (lane == 0) {
            brow[c * 2] = (uint32_t)m;
            brow[c * 2 + 1] = (uint32_t)(m >> 32);
        }
    }
}

// ---------------- fp32 [N,D] -> bf16 [N,D] + bf16 [D,N] ---------------------
__global__ __launch_bounds__(256) void prep_hidden(const float* __restrict__ in,
                                                   unsigned short* __restrict__ hb,
                                                   unsigned short* __restrict__ hT) {
    __shared__ unsigned short tile[64][65];
    const int b = blockIdx.z;
    in += (size_t)b * N_ * D_;
    hb += (size_t)b * N_ * D_;
    hT += (size_t)b * D_ * N_;
    const int n0 = blockIdx.y * 64, d0 = blockIdx.x * 64;
    const int t = threadIdx.x;
    const int tr = t >> 4, tc = (t & 15) * 4;
#pragma unroll
    for (int q = 0; q < 4; ++q) {
        const int rr = q * 16 + tr;
        const float4 f = *(const float4*)&in[(size_t)(n0 + rr) * D_ + d0 + tc];
        unsigned short h0 = f2bf(f.x), h1 = f2bf(f.y), h2 = f2bf(f.z), h3 = f2bf(f.w);
        *(ushort4*)&hb[(size_t)(n0 + rr) * D_ + d0 + tc] = make_ushort4(h0, h1, h2, h3);
        tile[rr][tc + 0] = h0; tile[rr][tc + 1] = h1;
        tile[rr][tc + 2] = h2; tile[rr][tc + 3] = h3;
    }
    __syncthreads();
#pragma unroll
    for (int q = 0; q < 4; ++q) {
        const int cc = q * 16 + tr;
        ushort4 o = make_ushort4(tile[tc + 0][cc], tile[tc + 1][cc],
                                 tile[tc + 2][cc], tile[tc + 3][cc]);
        *(ushort4*)&hT[(size_t)(d0 + cc) * N_ + n0 + tc] = o;
    }
}

// ---------------- tiny: w[D,D] f32 -> wT[D,D] bf16 --------------------------
__global__ __launch_bounds__(256) void cast_wT(const float* __restrict__ w,
                                               unsigned short* __restrict__ wT) {
    const int gid = blockIdx.x * 256 + threadIdx.x;
    const int i = gid >> 8, j = gid & 255;
    wT[j * D_ + i] = f2bf(w[i * D_ + j]);
}

// ---- PV slab reduce: edge_h = (slab0+slab1)/rsum + eln; also f32 [D,E] T ---
__global__ __launch_bounds__(256) void reduce_pv(const float* __restrict__ slab,
                                                 const unsigned short* __restrict__ eln,
                                                 const float* __restrict__ rsum,
                                                 unsigned short* __restrict__ eh,
                                                 float* __restrict__ ehT) {
    __shared__ float tile[64][65];
    const int b = blockIdx.z;
    const float* s0 = slab + (size_t)(b * 2) * E_ * D_;
    const float* s1 = slab + (size_t)(b * 2 + 1) * E_ * D_;
    const int e0 = blockIdx.y * 64, d0 = blockIdx.x * 64;
    const int t = threadIdx.x;
    const int tr = t >> 4, tc = (t & 15) * 4;
#pragma unroll
    for (int q = 0; q < 4; ++q) {
        const int rr = q * 16 + tr;
        const int row = e0 + rr;
        const float4 v0 = *(const float4*)&s0[(size_t)row * D_ + d0 + tc];
        const float4 v1 = *(const float4*)&s1[(size_t)row * D_ + d0 + tc];
        const float inv = 1.0f / rsum[(size_t)b * E_ + row];
        const ushort4 el = *(const ushort4*)&eln[(size_t)b * E_ * D_ + (size_t)row * D_ + d0 + tc];
        const float x0 = (v0.x + v1.x) * inv + bf2f(el.x);
        const float x1 = (v0.y + v1.y) * inv + bf2f(el.y);
        const float x2 = (v0.z + v1.z) * inv + bf2f(el.z);
        const float x3 = (v0.w + v1.w) * inv + bf2f(el.w);
        *(ushort4*)&eh[(size_t)b * E_ * D_ + (size_t)row * D_ + d0 + tc] =
            make_ushort4(f2bf(x0), f2bf(x1), f2bf(x2), f2bf(x3));
        tile[rr][tc + 0] = x0; tile[rr][tc + 1] = x1;
        tile[rr][tc + 2] = x2; tile[rr][tc + 3] = x3;
    }
    __syncthreads();
#pragma unroll
    for (int q = 0; q < 4; ++q) {
        const int cc = q * 16 + tr;
        float4 o = make_float4(tile[tc + 0][cc], tile[tc + 1][cc],
                               tile[tc + 2][cc], tile[tc + 3][cc]);
        *(float4*)&ehT[(size_t)b * D_ * E_ + (size_t)(d0 + cc) * E_ + e0 + tc] = o;
    }
}

// ---- edge_hsT[d,e] = ehT[d,e] / lsum[e]  (f32 in, bf16 out, [B,D,E]) -------
__global__ __launch_bounds__(256) void scale_ehT(const float* __restrict__ ehT,
                                                 const float* __restrict__ lsum,
                                                 unsigned short* __restrict__ ehs) {
    const size_t base = ((size_t)blockIdx.x * 256 + threadIdx.x) * 8;
    const int b = (int)(base / ((size_t)D_ * E_));
    const int e = (int)(base % E_);
    const float4 f0 = *(const float4*)&ehT[base];
    const float4 f1 = *(const float4*)&ehT[base + 4];
    const float4 l0 = *(const float4*)&lsum[(size_t)b * E_ + e];
    const float4 l1 = *(const float4*)&lsum[(size_t)b * E_ + e + 4];
    us8 o;
    o[0] = f2bf(f0.x / l0.x); o[1] = f2bf(f0.y / l0.y);
    o[2] = f2bf(f0.z / l0.z); o[3] = f2bf(f0.w / l0.w);
    o[4] = f2bf(f1.x / l1.x); o[5] = f2bf(f1.y / l1.y);
    o[6] = f2bf(f1.z / l1.z); o[7] = f2bf(f1.w / l1.w);
    *(us8*)&ehs[base] = o;
}

// ---- colsum_exp: lsum[e] += sum_n exp(S2T[n,e])  (raw-masked bf16 input) ---
__global__ __launch_bounds__(256) void colsum_exp(const unsigned short* __restrict__ S,
                                                  float* __restrict__ lsum) {
    const int b = blockIdx.y;
    const int n0 = blockIdx.x * 64;
    const int t = threadIdx.x;
    const unsigned short* p = S + ((size_t)b * N_ + n0) * E_ + t * 8;
    float s[8] = {};
    for (int i = 0; i < 64; ++i) {
        us8 v = *(const us8*)&p[(size_t)i * E_];
#pragma unroll
        for (int j = 0; j < 8; ++j) s[j] += __expf(bf2f(v[j]));
    }
#pragma unroll
    for (int j = 0; j < 8; ++j)
        atomicAdd(&lsum[(size_t)b * E_ + t * 8 + j], s[j]);
}

// ---------------- MFMA NT GEMM: C[m,n] = sum_k A[m,k]*Bt[n,k] ---------------
// 128x128 tile, BK=32, global_load_lds w=16, swizzled LDS.
// MODE: M_BF16 raw bf16 store | M_MASK bf16 store of scale*acc with mask->-9e15
//       | M_F32 raw f32 store.
// MASKOR: 1 = mask rows are M (S1: [E,N]); 2 = mask cols are N-dim (S2T: [N,E]).
// AEXP: A-operand staged via VGPR with exp() applied. ASUM: in-register row
// sums of exp(A) -> atomicAdd to sums (blockIdx.x==0 only). SPLIT: split-K=2.
#define M_BF16 0
#define M_MASK 1
#define M_F32 2

template <int MODE, int MASKOR, int AEXP, int ASUM, int SPLIT>
__global__ __launch_bounds__(256) void mfma_gemm_nt(
        const short* __restrict__ A, const short* __restrict__ Bm,
        void* __restrict__ Cv, const uint32_t* __restrict__ bits,
        float* __restrict__ sums,
        int K, int ldc, size_t sA, size_t sB, size_t sC, float scale) {
    __shared__ __align__(16) short ls[(MODE == M_F32) ? 8192 : 16896];
    __shared__ uint32_t mwords[MASKOR ? 512 : 4];
    short* lsA = ls;
    short* lsB = ls + 4096;
    const int zb = blockIdx.z;
    const int b = SPLIT ? (zb >> 1) : zb;
    A += (size_t)b * sA;
    Bm += (size_t)b * sB;
    const int m0 = blockIdx.y * 128, n0 = blockIdx.x * 128;
    const int tid = threadIdx.x, wid = tid >> 6, lane = tid & 63;
    const int l15 = lane & 15, kg = lane >> 4;
    const int wr = wid >> 1, wc = wid & 1;

    if (MASKOR) {
        const uint32_t* bb = bits + (size_t)b * E_ * (N_ / 32);
#pragma unroll
        for (int q = 0; q < 2; ++q) {
            const int idx = q * 256 + tid;
            mwords[idx] = (MASKOR == 1)
                ? bb[(size_t)(m0 + (idx >> 2)) * (N_ / 32) + (n0 >> 5) + (idx & 3)]
                : bb[(size_t)(n0 + (idx >> 2)) * (N_ / 32) + (m0 >> 5) + (idx & 3)];
        }
    }

    int aoff[4], boff[4];
#pragma unroll
    for (int i = 0; i < 4; ++i) {
        const int ra = wr * 64 + i * 16 + l15;
        aoff[i] = ra * 32 + (((kg + (ra >> 1)) & 3) << 3);
        const int rb = wc * 64 + i * 16 + l15;
        boff[i] = rb * 32 + (((kg + (rb >> 1)) & 3) << 3);
    }
    const f32x4 zero = {0.f, 0.f, 0.f, 0.f};
    f32x4 acc[4][4];
#pragma unroll
    for (int i = 0; i < 4; ++i)
#pragma unroll
        for (int j = 0; j < 4; ++j) acc[i][j] = zero;

    float rsumLoc = 0.f;  // AEXP+ASUM: partial row sum for row tid>>1
    const int ar = tid >> 1, ah = tid & 1;  // AEXP: row / 16-elem half

    const int kt0 = SPLIT ? (zb & 1) * (K >> 1) : 0;
    const int ktE = SPLIT ? kt0 + (K >> 1) : K;
    for (int kt = kt0; kt < ktE; kt += 32) {
        __syncthreads();
        if (AEXP) {
            // A: global->VGPR, exp, ->LDS (swizzled); B: global_load_lds
            const short* ga = A + (size_t)(m0 + ar) * K + kt + ah * 16;
            const us8 raw0 = *(const us8*)ga;
            const us8 raw1 = *(const us8*)(ga + 8);
            us8 e0, e1;
#pragma unroll
            for (int j = 0; j < 8; ++j) {
                const float x = __expf(bf2f(raw0[j]));
                if (ASUM) rsumLoc += x;
                e0[j] = f2bf(x);
            }
#pragma unroll
            for (int j = 0; j < 8; ++j) {
                const float x = __expf(bf2f(raw1[j]));
                if (ASUM) rsumLoc += x;
                e1[j] = f2bf(x);
            }
            const int p0 = (ah * 2 + (ar >> 1)) & 3;
            const int p1 = (ah * 2 + 1 + (ar >> 1)) & 3;
            *(us8*)&lsA[ar * 32 + p0 * 8] = e0;
            *(us8*)&lsA[ar * 32 + p1 * 8] = e1;
#pragma unroll
            for (int q = 0; q < 2; ++q) {
                const int c = q * 256 + tid;
                const int r = c >> 2;
                const int kc = ((c & 3) - (r >> 1)) & 3;
                const short* gb = Bm + (size_t)(n0 + r) * K + kt + kc * 8;
                __builtin_amdgcn_global_load_lds((const AS1 void*)gb,
                    (AS3 void*)(lsB + (q * 256 + wid * 64) * 8), 16, 0, 0);
            }
        } else {
#pragma unroll
            for (int q = 0; q < 2; ++q) {
                const int c = q * 256 + tid;
                const int r = c >> 2;
                const int kc = ((c & 3) - (r >> 1)) & 3;
                const short* ga = A + (size_t)(m0 + r) * K + kt + kc * 8;
                __builtin_amdgcn_global_load_lds((const AS1 void*)ga,
                    (AS3 void*)(lsA + (q * 256 + wid * 64) * 8), 16, 0, 0);
                const short* gb = Bm + (size_t)(n0 + r) * K + kt + kc * 8;
                __builtin_amdgcn_global_load_lds((const AS1 void*)gb,
                    (AS3 void*)(lsB + (q * 256 + wid * 64) * 8), 16, 0, 0);
            }
        }
        __syncthreads();
        bf16x8 fa[4], fb[4];
#pragma unroll
        for (int i = 0; i < 4; ++i) fa[i] = *(const bf16x8*)(lsA + aoff[i]);
#pragma unroll
        for (int j = 0; j < 4; ++j) fb[j] = *(const bf16x8*)(lsB + boff[j]);
#pragma unroll
        for (int i = 0; i < 4; ++i)
#pragma unroll
            for (int j = 0; j < 4; ++j)
                acc[i][j] = __builtin_amdgcn_mfma_f32_16x16x32_bf16(fa[i], fb[j], acc[i][j], 0, 0, 0);
    }

    if (AEXP && ASUM) {
        const float tot = rsumLoc + __shfl_xor(rsumLoc, 1, 64);
        if (ah == 0 && blockIdx.x == 0)
            atomicAdd(&sums[(size_t)b * E_ + m0 + ar], tot);
    }

    __syncthreads();  // fragment reads done; ls free for repack

    if (MODE == M_F32) {
        float* C = (float*)Cv + (SPLIT ? (size_t)zb * sC : (size_t)b * sC);
        float* lsF = (float*)ls;
#pragma unroll
        for (int h = 0; h < 4; ++h) {
            if (wr == (h >> 1)) {
#pragma unroll
                for (int ii = 0; ii < 2; ++ii) {
                    const int i = (h & 1) * 2 + ii;
#pragma unroll
                    for (int j = 0; j < 4; ++j)
#pragma unroll
                        for (int r = 0; r < 4; ++r) {
                            const int rl = ii * 16 + kg * 4 + r;
                            const int cl = wc * 64 + j * 16 + l15;
                            lsF[rl * 128 + cl] = acc[i][j][r];
                        }
                }
            }
            __syncthreads();
#pragma unroll
            for (int si = 0; si < 4; ++si) {
                const int row = (tid >> 5) + si * 8;
                const int colb = (tid & 31) * 4;
                float4 v = *(float4*)&lsF[row * 128 + colb];
                *(float4*)&C[(size_t)(m0 + h * 32 + row) * ldc + n0 + colb] = v;
            }
            __syncthreads();
        }
    } else {
        // single-phase bf16 repack, stride 132 (conflict-free), all waves active
        unsigned short* C = (unsigned short*)Cv + (size_t)b * sC;
#pragma unroll
        for (int i = 0; i < 4; ++i) {
#pragma unroll
            for (int r = 0; r < 4; ++r) {
                const int rowfull = wr * 64 + i * 16 + kg * 4 + r;
                uint64_t mwr = 0;
                if (MODE == M_MASK && MASKOR == 1)
                    mwr = *(const uint64_t*)&mwords[rowfull * 4 + wc * 2];
#pragma unroll
                for (int j = 0; j < 4; ++j) {
                    const int cl = wc * 64 + j * 16 + l15;
                    float v = acc[i][j][r];
                    if (MODE == M_MASK) {
                        v *= scale;
                        uint32_t bit;
                        if (MASKOR == 1) {
                            bit = (uint32_t)(mwr >> (j * 16 + l15)) & 1u;
                        } else {
                            const uint64_t mwc = *(const uint64_t*)&mwords[cl * 4 + wr * 2];
                            bit = (uint32_t)(mwc >> (i * 16 + kg * 4 + r)) & 1u;
                        }
                        if (!bit) v = INF_SUB;
                    }
                    ls[rowfull * 132 + cl] = (short)f2bf(v);
                }
            }
        }
        __syncthreads();
#pragma unroll
        for (int si = 0; si < 8; ++si) {
            const int row = (tid >> 4) + si * 16;
            const int col = (tid & 15) * 8;
            us8 val = *(us8*)&ls[row * 132 + col];
            *(us8*)&C[(size_t)(m0 + row) * ldc + n0 + col] = val;
        }
    }
}

// ---------------------------------------------------------------------------
extern "C" void kernel_launch(void* const* d_in, const int* in_sizes, int n_in,
                              void* d_out, int out_size, void* d_ws, size_t ws_size,
                              hipStream_t stream) {
    const float* hidden = (const float*)d_in[0];    // [B,N,D]
    const int* ht = (const int*)d_in[1];            // [B,E,N]
    const float* edge_emb = (const float*)d_in[2];  // [B,E,D]
    const float* wnk = (const float*)d_in[3];       // [D,D]
    const float* wek = (const float*)d_in[4];       // [D,D]
    const float* gamma = (const float*)d_in[5];     // [D]
    const float* beta = (const float*)d_in[6];      // [D]
    float* out = (float*)d_out;                     // [B,N,D]
    (void)in_sizes; (void)n_in; (void)out_size; (void)ws_size;

    char* w = (char*)d_ws;
    unsigned short* SP = (unsigned short*)w;         w += (size_t)B_ * E_ * N_ * 2;   // 134MB (S1 [E,N], then S2T [N,E])
    unsigned short* hidden_bf = (unsigned short*)w;  w += (size_t)B_ * N_ * D_ * 2;
    unsigned short* hiddenT_bf = (unsigned short*)w; w += (size_t)B_ * D_ * N_ * 2;
    unsigned short* node_k_bf = (unsigned short*)w;  w += (size_t)B_ * N_ * D_ * 2;
    unsigned short* eln_bf = (unsigned short*)w;     w += (size_t)B_ * E_ * D_ * 2;
    unsigned short* edge_h_bf = (unsigned short*)w;  w += (size_t)B_ * E_ * D_ * 2;
    float* ehT_f32 = (float*)w;                      w += (size_t)B_ * D_ * E_ * 4;
    unsigned short* ehsT_bf = (unsigned short*)w;    w += (size_t)B_ * D_ * E_ * 2;
    unsigned short* edge_k_bf = (unsigned short*)w;  w += (size_t)B_ * E_ * D_ * 2;
    float* slabs = (float*)w;                        w += (size_t)B_ * 2 * E_ * D_ * 4;
    uint32_t* bits = (uint32_t*)w;                   w += (size_t)B_ * E_ * (N_ / 32) * 4;
    float* rsum = (float*)w;                         w += (size_t)B_ * E_ * 4;
    float* lsum = (float*)w;                         w += (size_t)B_ * E_ * 4;
    unsigned short* wnkT = (unsigned short*)w;       w += (size_t)D_ * D_ * 2;
    unsigned short* wekT = (unsigned short*)w;       w += (size_t)D_ * D_ * 2;

    const float scale = 0.0625f;  // 1/sqrt(256)

    // prep
    prep_hidden<<<dim3(D_ / 64, N_ / 64, B_), 256, 0, stream>>>(hidden, hidden_bf, hiddenT_bf);
    cast_wT<<<D_ * D_ / 256, 256, 0, stream>>>(wnk, wnkT);
    cast_wT<<<D_ * D_ / 256, 256, 0, stream>>>(wek, wekT);
    ln_kernel<<<B_ * E_, 256, 0, stream>>>(edge_emb, gamma, beta, eln_bf);
    pack_mask<<<B_ * E_, 256, 0, stream>>>(ht, bits);
    hipMemsetAsync(rsum, 0, (size_t)B_ * E_ * 8, stream);  // rsum + lsum (adjacent)

    // node_k = hidden @ wnk
    mfma_gemm_nt<M_BF16, 0, 0, 0, 0><<<dim3(D_ / 128, (B_ * N_) / 128, 1), 256, 0, stream>>>(
        (const short*)hidden_bf, (const short*)wnkT, node_k_bf, nullptr, nullptr,
        D_, D_, 0, 0, 0, 1.f);
    // S1[e,n] = mask(eln . node_k * scale)  (raw-masked bf16 scores)
    mfma_gemm_nt<M_MASK, 1, 0, 0, 0><<<dim3(N_ / 128, E_ / 128, B_), 256, 0, stream>>>(
        (const short*)eln_bf, (const short*)node_k_bf, SP, bits, nullptr,
        D_, N_, (size_t)E_ * D_, (size_t)N_ * D_, (size_t)E_ * N_, scale);
    // PV slabs: slab[b*2+s][e,d] = sum_{n in half s} exp(S1[e,n])*hidden[n,d];
    // rsum[e] accumulated in-register (blockIdx.x==0 blocks only)
    mfma_gemm_nt<M_F32, 0, 1, 1, 1><<<dim3(D_ / 128, E_ / 128, B_ * 2), 256, 0, stream>>>(
        (const short*)SP, (const short*)hiddenT_bf, slabs, nullptr, rsum,
        N_, D_, (size_t)E_ * N_, (size_t)D_ * N_, (size_t)E_ * D_, 1.f);
    // edge_h = (slab0+slab1)/rsum + eln  -> bf16 [E,D] and f32 [D,E]
    reduce_pv<<<dim3(D_ / 64, E_ / 64, B_), 256, 0, stream>>>(
        slabs, eln_bf, rsum, edge_h_bf, ehT_f32);
    // edge_k = edge_h @ wek
    mfma_gemm_nt<M_BF16, 0, 0, 0, 0><<<dim3(D_ / 128, (B_ * E_) / 128, 1), 256, 0, stream>>>(
        (const short*)edge_h_bf, (const short*)wekT, edge_k_bf, nullptr, nullptr,
        D_, D_, 0, 0, 0, 1.f);
    // S2T[n,e] = mask(node_k . edge_k * scale)  (raw-masked bf16 scores)
    mfma_gemm_nt<M_MASK, 2, 0, 0, 0><<<dim3(E_ / 128, N_ / 128, B_), 256, 0, stream>>>(
        (const short*)node_k_bf, (const short*)edge_k_bf, SP, bits, nullptr,
        D_, E_, (size_t)N_ * D_, (size_t)E_ * D_, (size_t)N_ * E_, scale);
    // lsum[e] = sum_n exp(S2T[n,e])
    colsum_exp<<<dim3(N_ / 64, B_), 256, 0, stream>>>(SP, lsum);
    // edge_hs[d,e] = ehT/lsum[e]
    scale_ehT<<<(B_ * D_ * E_) / (256 * 8), 256, 0, stream>>>(ehT_f32, lsum, ehsT_bf);
    // out[n,d] = sum_e exp(S2T[n,e]) * edge_hs[d,e]  (exp in A-path)
    mfma_gemm_nt<M_F32, 0, 1, 0, 0><<<dim3(D_ / 128, N_ / 128, B_), 256, 0, stream>>>(
        (const short*)SP, (const short*)ehsT_bf, out, nullptr, nullptr,
        E_, D_, (size_t)N_ * E_, (size_t)D_ * E_, (size_t)N_ * D_, 1.f);
}

// Round 6
// 791.073 us; speedup vs baseline: 3.3243x; 1.0974x over previous
//
#include <hip/hip_runtime.h>
#include <hip/hip_bf16.h>
#include <stdint.h>

// R6: BK=64 K-loop (half the barrier-drain events; K=256 GEMMs now 4 iters),
// lsum (stage-2 softmax denominator) folded back into the lean S2 epilogue,
// colsum_exp pass deleted. Everything else as R5.

#define B_ 8
#define N_ 4096
#define E_ 2048
#define D_ 256
#define INF_SUB (-9.0e15f)

typedef short bf16x8 __attribute__((ext_vector_type(8)));
typedef float f32x4 __attribute__((ext_vector_type(4)));
typedef unsigned short us8 __attribute__((ext_vector_type(8)));

#define AS1 __attribute__((address_space(1)))
#define AS3 __attribute__((address_space(3)))

__device__ __forceinline__ unsigned short f2bf(float f) {
    union { float f; unsigned int u; } v; v.f = f;
    unsigned int r = v.u + 0x7fffu + ((v.u >> 16) & 1u);
    return (unsigned short)(r >> 16);
}
__device__ __forceinline__ float bf2f(unsigned short h) {
    union { unsigned int u; float f; } v; v.u = ((unsigned int)h) << 16;
    return v.f;
}
__device__ __forceinline__ float waveReduceSum(float v) {
#pragma unroll
    for (int o = 32; o > 0; o >>= 1) v += __shfl_xor(v, o, 64);
    return v;
}

// ---------------- LayerNorm over D=256 -> bf16 ------------------------------
__global__ __launch_bounds__(256) void ln_kernel(const float* __restrict__ x,
                                                 const float* __restrict__ gamma,
                                                 const float* __restrict__ beta,
                                                 unsigned short* __restrict__ yb) {
    __shared__ float red[8];
    const int row = blockIdx.x;
    const int t = threadIdx.x;
    const int lane = t & 63, wid = t >> 6;
    const float v = x[(size_t)row * D_ + t];
    float s = waveReduceSum(v);
    if (lane == 0) red[wid] = s;
    __syncthreads();
    const float mu = (red[0] + red[1] + red[2] + red[3]) * (1.0f / D_);
    const float d = v - mu;
    float s2 = waveReduceSum(d * d);
    if (lane == 0) red[4 + wid] = s2;
    __syncthreads();
    const float var = (red[4] + red[5] + red[6] + red[7]) * (1.0f / D_);
    yb[(size_t)row * D_ + t] = f2bf(gamma[t] * d * rsqrtf(var + 1e-5f) + beta[t]);
}

// ---------------- pack ht -> bitmask: bits[b][e][n>>5] bit (n&31) -----------
__global__ __launch_bounds__(256) void pack_mask(const int* __restrict__ ht,
                                                 uint32_t* __restrict__ bits) {
    const int row = blockIdx.x;
    const int t = threadIdx.x, wid = t >> 6, lane = t & 63;
    const int* hrow = ht + (size_t)row * N_;
    uint32_t* brow = bits + (size_t)row * (N_ / 32);
#pragma unroll
    for (int i = 0; i < 16; ++i) {
        const int c = wid * 16 + i;
        const int v = hrow[c * 64 + lane];
        unsigned long long m = __ballot(v > 0);
        if (lane == 0) {
            brow[c * 2] = (uint32_t)m;
            brow[c * 2 + 1] = (uint32_t)(m >> 32);
        }
    }
}

// ---------------- fp32 [N,D] -> bf16 [N,D] + bf16 [D,N] ---------------------
__global__ __launch_bounds__(256) void prep_hidden(const float* __restrict__ in,
                                                   unsigned short* __restrict__ hb,
                                                   unsigned short* __restrict__ hT) {
    __shared__ unsigned short tile[64][65];
    const int b = blockIdx.z;
    in += (size_t)b * N_ * D_;
    hb += (size_t)b * N_ * D_;
    hT += (size_t)b * D_ * N_;
    const int n0 = blockIdx.y * 64, d0 = blockIdx.x * 64;
    const int t = threadIdx.x;
    const int tr = t >> 4, tc = (t & 15) * 4;
#pragma unroll
    for (int q = 0; q < 4; ++q) {
        const int rr = q * 16 + tr;
        const float4 f = *(const float4*)&in[(size_t)(n0 + rr) * D_ + d0 + tc];
        unsigned short h0 = f2bf(f.x), h1 = f2bf(f.y), h2 = f2bf(f.z), h3 = f2bf(f.w);
        *(ushort4*)&hb[(size_t)(n0 + rr) * D_ + d0 + tc] = make_ushort4(h0, h1, h2, h3);
        tile[rr][tc + 0] = h0; tile[rr][tc + 1] = h1;
        tile[rr][tc + 2] = h2; tile[rr][tc + 3] = h3;
    }
    __syncthreads();
#pragma unroll
    for (int q = 0; q < 4; ++q) {
        const int cc = q * 16 + tr;
        ushort4 o = make_ushort4(tile[tc + 0][cc], tile[tc + 1][cc],
                                 tile[tc + 2][cc], tile[tc + 3][cc]);
        *(ushort4*)&hT[(size_t)(d0 + cc) * N_ + n0 + tc] = o;
    }
}

// ---------------- tiny: w[D,D] f32 -> wT[D,D] bf16 --------------------------
__global__ __launch_bounds__(256) void cast_wT(const float* __restrict__ w,
                                               unsigned short* __restrict__ wT) {
    const int gid = blockIdx.x * 256 + threadIdx.x;
    const int i = gid >> 8, j = gid & 255;
    wT[j * D_ + i] = f2bf(w[i * D_ + j]);
}

// ---- PV slab reduce: edge_h = (slab0+slab1)/rsum + eln; also f32 [D,E] T ---
__global__ __launch_bounds__(256) void reduce_pv(const float* __restrict__ slab,
                                                 const unsigned short* __restrict__ eln,
                                                 const float* __restrict__ rsum,
                                                 unsigned short* __restrict__ eh,
                                                 float* __restrict__ ehT) {
    __shared__ float tile[64][65];
    const int b = blockIdx.z;
    const float* s0 = slab + (size_t)(b * 2) * E_ * D_;
    const float* s1 = slab + (size_t)(b * 2 + 1) * E_ * D_;
    const int e0 = blockIdx.y * 64, d0 = blockIdx.x * 64;
    const int t = threadIdx.x;
    const int tr = t >> 4, tc = (t & 15) * 4;
#pragma unroll
    for (int q = 0; q < 4; ++q) {
        const int rr = q * 16 + tr;
        const int row = e0 + rr;
        const float4 v0 = *(const float4*)&s0[(size_t)row * D_ + d0 + tc];
        const float4 v1 = *(const float4*)&s1[(size_t)row * D_ + d0 + tc];
        const float inv = 1.0f / rsum[(size_t)b * E_ + row];
        const ushort4 el = *(const ushort4*)&eln[(size_t)b * E_ * D_ + (size_t)row * D_ + d0 + tc];
        const float x0 = (v0.x + v1.x) * inv + bf2f(el.x);
        const float x1 = (v0.y + v1.y) * inv + bf2f(el.y);
        const float x2 = (v0.z + v1.z) * inv + bf2f(el.z);
        const float x3 = (v0.w + v1.w) * inv + bf2f(el.w);
        *(ushort4*)&eh[(size_t)b * E_ * D_ + (size_t)row * D_ + d0 + tc] =
            make_ushort4(f2bf(x0), f2bf(x1), f2bf(x2), f2bf(x3));
        tile[rr][tc + 0] = x0; tile[rr][tc + 1] = x1;
        tile[rr][tc + 2] = x2; tile[rr][tc + 3] = x3;
    }
    __syncthreads();
#pragma unroll
    for (int q = 0; q < 4; ++q) {
        const int cc = q * 16 + tr;
        float4 o = make_float4(tile[tc + 0][cc], tile[tc + 1][cc],
                               tile[tc + 2][cc], tile[tc + 3][cc]);
        *(float4*)&ehT[(size_t)b * D_ * E_ + (size_t)(d0 + cc) * E_ + e0 + tc] = o;
    }
}

// ---- edge_hsT[d,e] = ehT[d,e] / lsum[e]  (f32 in, bf16 out, [B,D,E]) -------
__global__ __launch_bounds__(256) void scale_ehT(const float* __restrict__ ehT,
                                                 const float* __restrict__ lsum,
                                                 unsigned short* __restrict__ ehs) {
    const size_t base = ((size_t)blockIdx.x * 256 + threadIdx.x) * 8;
    const int b = (int)(base / ((size_t)D_ * E_));
    const int e = (int)(base % E_);
    const float4 f0 = *(const float4*)&ehT[base];
    const float4 f1 = *(const float4*)&ehT[base + 4];
    const float4 l0 = *(const float4*)&lsum[(size_t)b * E_ + e];
    const float4 l1 = *(const float4*)&lsum[(size_t)b * E_ + e + 4];
    us8 o;
    o[0] = f2bf(f0.x / l0.x); o[1] = f2bf(f0.y / l0.y);
    o[2] = f2bf(f0.z / l0.z); o[3] = f2bf(f0.w / l0.w);
    o[4] = f2bf(f1.x / l1.x); o[5] = f2bf(f1.y / l1.y);
    o[6] = f2bf(f1.z / l1.z); o[7] = f2bf(f1.w / l1.w);
    *(us8*)&ehs[base] = o;
}

// ---------------- MFMA NT GEMM: C[m,n] = sum_k A[m,k]*Bt[n,k] ---------------
// 128x128 tile, BK=64 (4 barrier-pairs at K=256), global_load_lds w=16,
// chunk-rotate swizzle mod 8. MODE/MASKOR/AEXP/ASUM/SPLIT as R5; CSUM adds
// column exp-sums (stage-2 lsum) in the M_MASK epilogue.
#define M_BF16 0
#define M_MASK 1
#define M_F32 2

template <int MODE, int MASKOR, int AEXP, int ASUM, int SPLIT, int CSUM>
__global__ __launch_bounds__(256) void mfma_gemm_nt(
        const short* __restrict__ A, const short* __restrict__ Bm,
        void* __restrict__ Cv, const uint32_t* __restrict__ bits,
        float* __restrict__ sums,
        int K, int ldc, size_t sA, size_t sB, size_t sC, float scale) {
    __shared__ __align__(16) short ls[(MODE == M_F32) ? 16384 : 16896];
    __shared__ uint32_t mwords[MASKOR ? 512 : 4];
    short* lsA = ls;              // 128 x 64 bf16 = 16 KB
    short* lsB = ls + 8192;       // 128 x 64 bf16 = 16 KB
    const int zb = blockIdx.z;
    const int b = SPLIT ? (zb >> 1) : zb;
    A += (size_t)b * sA;
    Bm += (size_t)b * sB;
    const int m0 = blockIdx.y * 128, n0 = blockIdx.x * 128;
    const int tid = threadIdx.x, wid = tid >> 6, lane = tid & 63;
    const int l15 = lane & 15, kg = lane >> 4;
    const int wr = wid >> 1, wc = wid & 1;

    if (MASKOR) {
        const uint32_t* bb = bits + (size_t)b * E_ * (N_ / 32);
#pragma unroll
        for (int q = 0; q < 2; ++q) {
            const int idx = q * 256 + tid;
            mwords[idx] = (MASKOR == 1)
                ? bb[(size_t)(m0 + (idx >> 2)) * (N_ / 32) + (n0 >> 5) + (idx & 3)]
                : bb[(size_t)(n0 + (idx >> 2)) * (N_ / 32) + (m0 >> 5) + (idx & 3)];
        }
    }

    // fragment LDS addressing: row r, k-chunk ck (8 shorts) stored at position
    // p = (ck + (r>>1)) & 7 within the 64-short row.
    int raoff[4], rota[4], rboff[4], rotb[4];
#pragma unroll
    for (int i = 0; i < 4; ++i) {
        const int ra = wr * 64 + i * 16 + l15;
        raoff[i] = ra * 64; rota[i] = kg + (ra >> 1);
        const int rb = wc * 64 + i * 16 + l15;
        rboff[i] = rb * 64; rotb[i] = kg + (rb >> 1);
    }
    const f32x4 zero = {0.f, 0.f, 0.f, 0.f};
    f32x4 acc[4][4];
#pragma unroll
    for (int i = 0; i < 4; ++i)
#pragma unroll
        for (int j = 0; j < 4; ++j) acc[i][j] = zero;

    float rsumLoc = 0.f;
    const int ar = tid >> 1, ah = tid & 1;  // AEXP: row / 32-k half

    const int kt0 = SPLIT ? (zb & 1) * (K >> 1) : 0;
    const int ktE = SPLIT ? kt0 + (K >> 1) : K;
    for (int kt = kt0; kt < ktE; kt += 64) {
        __syncthreads();
        if (AEXP) {
            // A: global->VGPR, exp, ->LDS swizzled; B: global_load_lds
            const short* ga = A + (size_t)(m0 + ar) * K + kt + ah * 32;
            us8 raw[4], ex[4];
#pragma unroll
            for (int c = 0; c < 4; ++c) raw[c] = *(const us8*)(ga + c * 8);
#pragma unroll
            for (int c = 0; c < 4; ++c)
#pragma unroll
                for (int j = 0; j < 8; ++j) {
                    const float x = __expf(bf2f(raw[c][j]));
                    if (ASUM) rsumLoc += x;
                    ex[c][j] = f2bf(x);
                }
#pragma unroll
            for (int c = 0; c < 4; ++c) {
                const int p = (ah * 4 + c + (ar >> 1)) & 7;
                *(us8*)&lsA[ar * 64 + p * 8] = ex[c];
            }
#pragma unroll
            for (int q = 0; q < 4; ++q) {
                const int c = q * 256 + tid;
                const int r = c >> 3;
                const int kc = ((c & 7) - (r >> 1)) & 7;
                const short* gb = Bm + (size_t)(n0 + r) * K + kt + kc * 8;
                __builtin_amdgcn_global_load_lds((const AS1 void*)gb,
                    (AS3 void*)(lsB + (q * 256 + wid * 64) * 8), 16, 0, 0);
            }
        } else {
#pragma unroll
            for (int q = 0; q < 4; ++q) {
                const int c = q * 256 + tid;
                const int r = c >> 3;
                const int kc = ((c & 7) - (r >> 1)) & 7;
                const short* ga = A + (size_t)(m0 + r) * K + kt + kc * 8;
                __builtin_amdgcn_global_load_lds((const AS1 void*)ga,
                    (AS3 void*)(lsA + (q * 256 + wid * 64) * 8), 16, 0, 0);
                const short* gb = Bm + (size_t)(n0 + r) * K + kt + kc * 8;
                __builtin_amdgcn_global_load_lds((const AS1 void*)gb,
                    (AS3 void*)(lsB + (q * 256 + wid * 64) * 8), 16, 0, 0);
            }
        }
        __syncthreads();
#pragma unroll
        for (int s = 0; s < 2; ++s) {
            bf16x8 fa[4], fb[4];
#pragma unroll
            for (int i = 0; i < 4; ++i)
                fa[i] = *(const bf16x8*)(lsA + raoff[i] + (((s * 4 + rota[i]) & 7) << 3));
#pragma unroll
            for (int j = 0; j < 4; ++j)
                fb[j] = *(const bf16x8*)(lsB + rboff[j] + (((s * 4 + rotb[j]) & 7) << 3));
#pragma unroll
            for (int i = 0; i < 4; ++i)
#pragma unroll
                for (int j = 0; j < 4; ++j)
                    acc[i][j] = __builtin_amdgcn_mfma_f32_16x16x32_bf16(fa[i], fb[j], acc[i][j], 0, 0, 0);
        }
    }

    if (AEXP && ASUM) {
        const float tot = rsumLoc + __shfl_xor(rsumLoc, 1, 64);
        if (ah == 0 && blockIdx.x == 0)
            atomicAdd(&sums[(size_t)b * E_ + m0 + ar], tot);
    }

    __syncthreads();  // fragment reads done; ls free for repack

    if (MODE == M_F32) {
        float* C = (float*)Cv + (SPLIT ? (size_t)zb * sC : (size_t)b * sC);
        float* lsF = (float*)ls;
#pragma unroll
        for (int h = 0; h < 4; ++h) {
            if (wr == (h >> 1)) {
#pragma unroll
                for (int ii = 0; ii < 2; ++ii) {
                    const int i = (h & 1) * 2 + ii;
#pragma unroll
                    for (int j = 0; j < 4; ++j)
#pragma unroll
                        for (int r = 0; r < 4; ++r) {
                            const int rl = ii * 16 + kg * 4 + r;
                            const int cl = wc * 64 + j * 16 + l15;
                            lsF[rl * 128 + cl] = acc[i][j][r];
                        }
                }
            }
            __syncthreads();
#pragma unroll
            for (int si = 0; si < 4; ++si) {
                const int row = (tid >> 5) + si * 8;
                const int colb = (tid & 31) * 4;
                float4 v = *(float4*)&lsF[row * 128 + colb];
                *(float4*)&C[(size_t)(m0 + h * 32 + row) * ldc + n0 + colb] = v;
            }
            __syncthreads();
        }
    } else {
        // single-phase bf16 repack, stride 132 (conflict-free), all waves active
        unsigned short* C = (unsigned short*)Cv + (size_t)b * sC;
        float evsum[4] = {0.f, 0.f, 0.f, 0.f};
#pragma unroll
        for (int i = 0; i < 4; ++i) {
#pragma unroll
            for (int r = 0; r < 4; ++r) {
                const int rowfull = wr * 64 + i * 16 + kg * 4 + r;
                uint64_t mwr = 0;
                if (MODE == M_MASK && MASKOR == 1)
                    mwr = *(const uint64_t*)&mwords[rowfull * 4 + wc * 2];
#pragma unroll
                for (int j = 0; j < 4; ++j) {
                    const int cl = wc * 64 + j * 16 + l15;
                    float v = acc[i][j][r];
                    if (MODE == M_MASK) {
                        v *= scale;
                        uint32_t bit;
                        if (MASKOR == 1) {
                            bit = (uint32_t)(mwr >> (j * 16 + l15)) & 1u;
                        } else {
                            const uint64_t mwc = *(const uint64_t*)&mwords[cl * 4 + wr * 2];
                            bit = (uint32_t)(mwc >> (i * 16 + kg * 4 + r)) & 1u;
                        }
                        if (!bit) v = INF_SUB;
                    }
                    ls[rowfull * 132 + cl] = (short)f2bf(v);
                    if (CSUM) evsum[j] += __expf(v);
                }
            }
        }
        __syncthreads();
#pragma unroll
        for (int si = 0; si < 8; ++si) {
            const int row = (tid >> 4) + si * 16;
            const int col = (tid & 15) * 8;
            us8 val = *(us8*)&ls[row * 132 + col];
            *(us8*)&C[(size_t)(m0 + row) * ldc + n0 + col] = val;
        }
        if (CSUM) {
#pragma unroll
            for (int j = 0; j < 4; ++j) {
                float cs = evsum[j];
                cs += __shfl_xor(cs, 16, 64);
                cs += __shfl_xor(cs, 32, 64);
                if (kg == 0)
                    atomicAdd(&sums[(size_t)b * E_ + n0 + wc * 64 + j * 16 + l15], cs);
            }
        }
    }
}

// ---------------------------------------------------------------------------
extern "C" void kernel_launch(void* const* d_in, const int* in_sizes, int n_in,
                              void* d_out, int out_size, void* d_ws, size_t ws_size,
                              hipStream_t stream) {
    const float* hidden = (const float*)d_in[0];    // [B,N,D]
    const int* ht = (const int*)d_in[1];            // [B,E,N]
    const float* edge_emb = (const float*)d_in[2];  // [B,E,D]
    const float* wnk = (const float*)d_in[3];       // [D,D]
    const float* wek = (const float*)d_in[4];       // [D,D]
    const float* gamma = (const float*)d_in[5];     // [D]
    const float* beta = (const float*)d_in[6];      // [D]
    float* out = (float*)d_out;                     // [B,N,D]
    (void)in_sizes; (void)n_in; (void)out_size; (void)ws_size;

    char* w = (char*)d_ws;
    unsigned short* SP = (unsigned short*)w;         w += (size_t)B_ * E_ * N_ * 2;   // 134MB (S1 [E,N], then S2T [N,E])
    unsigned short* hidden_bf = (unsigned short*)w;  w += (size_t)B_ * N_ * D_ * 2;
    unsigned short* hiddenT_bf = (unsigned short*)w; w += (size_t)B_ * D_ * N_ * 2;
    unsigned short* node_k_bf = (unsigned short*)w;  w += (size_t)B_ * N_ * D_ * 2;
    unsigned short* eln_bf = (unsigned short*)w;     w += (size_t)B_ * E_ * D_ * 2;
    unsigned short* edge_h_bf = (unsigned short*)w;  w += (size_t)B_ * E_ * D_ * 2;
    float* ehT_f32 = (float*)w;                      w += (size_t)B_ * D_ * E_ * 4;
    unsigned short* ehsT_bf = (unsigned short*)w;    w += (size_t)B_ * D_ * E_ * 2;
    unsigned short* edge_k_bf = (unsigned short*)w;  w += (size_t)B_ * E_ * D_ * 2;
    float* slabs = (float*)w;                        w += (size_t)B_ * 2 * E_ * D_ * 4;
    uint32_t* bits = (uint32_t*)w;                   w += (size_t)B_ * E_ * (N_ / 32) * 4;
    float* rsum = (float*)w;                         w += (size_t)B_ * E_ * 4;
    float* lsum = (float*)w;                         w += (size_t)B_ * E_ * 4;
    unsigned short* wnkT = (unsigned short*)w;       w += (size_t)D_ * D_ * 2;
    unsigned short* wekT = (unsigned short*)w;       w += (size_t)D_ * D_ * 2;

    const float scale = 0.0625f;  // 1/sqrt(256)

    // prep
    prep_hidden<<<dim3(D_ / 64, N_ / 64, B_), 256, 0, stream>>>(hidden, hidden_bf, hiddenT_bf);
    cast_wT<<<D_ * D_ / 256, 256, 0, stream>>>(wnk, wnkT);
    cast_wT<<<D_ * D_ / 256, 256, 0, stream>>>(wek, wekT);
    ln_kernel<<<B_ * E_, 256, 0, stream>>>(edge_emb, gamma, beta, eln_bf);
    pack_mask<<<B_ * E_, 256, 0, stream>>>(ht, bits);
    hipMemsetAsync(rsum, 0, (size_t)B_ * E_ * 8, stream);  // rsum + lsum (adjacent)

    // node_k = hidden @ wnk
    mfma_gemm_nt<M_BF16, 0, 0, 0, 0, 0><<<dim3(D_ / 128, (B_ * N_) / 128, 1), 256, 0, stream>>>(
        (const short*)hidden_bf, (const short*)wnkT, node_k_bf, nullptr, nullptr,
        D_, D_, 0, 0, 0, 1.f);
    // S1[e,n] = mask(eln . node_k * scale)  (raw-masked bf16 scores)
    mfma_gemm_nt<M_MASK, 1, 0, 0, 0, 0><<<dim3(N_ / 128, E_ / 128, B_), 256, 0, stream>>>(
        (const short*)eln_bf, (const short*)node_k_bf, SP, bits, nullptr,
        D_, N_, (size_t)E_ * D_, (size_t)N_ * D_, (size_t)E_ * N_, scale);
    // PV slabs: slab[b*2+s][e,d] = sum_{n in half s} exp(S1[e,n])*hidden[n,d];
    // rsum[e] accumulated in-register (blockIdx.x==0 blocks only)
    mfma_gemm_nt<M_F32, 0, 1, 1, 1, 0><<<dim3(D_ / 128, E_ / 128, B_ * 2), 256, 0, stream>>>(
        (const short*)SP, (const short*)hiddenT_bf, slabs, nullptr, rsum,
        N_, D_, (size_t)E_ * N_, (size_t)D_ * N_, (size_t)E_ * D_, 1.f);
    // edge_h = (slab0+slab1)/rsum + eln  -> bf16 [E,D] and f32 [D,E]
    reduce_pv<<<dim3(D_ / 64, E_ / 64, B_), 256, 0, stream>>>(
        slabs, eln_bf, rsum, edge_h_bf, ehT_f32);
    // edge_k = edge_h @ wek
    mfma_gemm_nt<M_BF16, 0, 0, 0, 0, 0><<<dim3(D_ / 128, (B_ * E_) / 128, 1), 256, 0, stream>>>(
        (const short*)edge_h_bf, (const short*)wekT, edge_k_bf, nullptr, nullptr,
        D_, D_, 0, 0, 0, 1.f);
    // S2T[n,e] = mask(node_k . edge_k * scale); lsum[e] += col exp-sums (CSUM)
    mfma_gemm_nt<M_MASK, 2, 0, 0, 0, 1><<<dim3(E_ / 128, N_ / 128, B_), 256, 0, stream>>>(
        (const short*)node_k_bf, (const short*)edge_k_bf, SP, bits, lsum,
        D_, E_, (size_t)N_ * D_, (size_t)E_ * D_, (size_t)N_ * E_, scale);
    // edge_hs[d,e] = ehT/lsum[e]
    scale_ehT<<<(B_ * D_ * E_) / (256 * 8), 256, 0, stream>>>(ehT_f32, lsum, ehsT_bf);
    // out[n,d] = sum_e exp(S2T[n,e]) * edge_hs[d,e]  (exp in A-path)
    mfma_gemm_nt<M_F32, 0, 1, 0, 0, 0><<<dim3(D_ / 128, N_ / 128, B_), 256, 0, stream>>>(
        (const short*)SP, (const short*)ehsT_bf, out, nullptr, nullptr,
        E_, D_, (size_t)N_ * E_, (size_t)D_ * E_, (size_t)N_ * D_, 1.f);
}